// Round 1
// baseline (4652.019 us; speedup 1.0000x reference)
//
#include <hip/hip_runtime.h>

#define DEV __device__ __forceinline__

using bf16x8 = __attribute__((ext_vector_type(8))) __bf16;
using f32x4  = __attribute__((ext_vector_type(4))) float;
using u16x8  = __attribute__((ext_vector_type(8))) unsigned short;

DEV unsigned short f2bf(float f) {
  unsigned u = __builtin_bit_cast(unsigned, f);
  u += 0x7fffu + ((u >> 16) & 1u);
  return (unsigned short)(u >> 16);
}
DEV float bf2f(unsigned short h) {
  unsigned u = ((unsigned)h) << 16;
  return __builtin_bit_cast(float, u);
}
DEV f32x4 mfma16(u16x8 a, u16x8 b, f32x4 c) {
  return __builtin_amdgcn_mfma_f32_16x16x32_bf16(
      __builtin_bit_cast(bf16x8, a), __builtin_bit_cast(bf16x8, b), c, 0, 0, 0);
}
DEV f32x4 zero4() { f32x4 z = {0.f, 0.f, 0.f, 0.f}; return z; }

// ---------------------------------------------------------------------------
// Generic bf16 MFMA GEMM: C[M x N] = A[M x K] * Bt[N x K]^T + bias, 128x128 tile
// ---------------------------------------------------------------------------
enum { EPI_BIAS = 0, EPI_RELU = 1, EPI_OUT = 2 };

template <int EPI>
__global__ __launch_bounds__(256) void gemm_k(
    const unsigned short* __restrict__ A, const unsigned short* __restrict__ Bt,
    const float* __restrict__ bias, unsigned short* __restrict__ C, int N, int K) {
  __shared__ unsigned short As[128 * 40];  // pad 32->40 (stride 80B, 16B-aligned)
  __shared__ unsigned short Bs[128 * 40];
  const int tid = threadIdx.x;
  const int lane = tid & 63, wv = tid >> 6;
  const int q = lane >> 4, ln = lane & 15;
  const int wr = wv >> 1, wc = wv & 1;
  const int m0 = blockIdx.y << 7, n0 = blockIdx.x << 7;

  f32x4 acc[4][4];
#pragma unroll
  for (int i = 0; i < 4; ++i)
#pragma unroll
    for (int j = 0; j < 4; ++j) acc[i][j] = zero4();

  const int r0 = tid >> 2, c0 = (tid & 3) << 3;  // chunk: 4 x 16B per 32-elem row
  const int r1 = r0 + 64;
  const unsigned short* Ap0 = A + (size_t)(m0 + r0) * K + c0;
  const unsigned short* Ap1 = A + (size_t)(m0 + r1) * K + c0;
  const unsigned short* Bp0 = Bt + (size_t)(n0 + r0) * K + c0;
  const unsigned short* Bp1 = Bt + (size_t)(n0 + r1) * K + c0;

  for (int kb = 0; kb < K; kb += 32) {
    __syncthreads();
    u16x8 a0 = *(const u16x8*)(Ap0 + kb);
    u16x8 a1 = *(const u16x8*)(Ap1 + kb);
    u16x8 b0 = *(const u16x8*)(Bp0 + kb);
    u16x8 b1 = *(const u16x8*)(Bp1 + kb);
    *(u16x8*)(As + r0 * 40 + c0) = a0;
    *(u16x8*)(As + r1 * 40 + c0) = a1;
    *(u16x8*)(Bs + r0 * 40 + c0) = b0;
    *(u16x8*)(Bs + r1 * 40 + c0) = b1;
    __syncthreads();
    u16x8 af[4];
#pragma unroll
    for (int mt = 0; mt < 4; ++mt)
      af[mt] = *(const u16x8*)(As + (wr * 64 + mt * 16 + ln) * 40 + q * 8);
#pragma unroll
    for (int nt = 0; nt < 4; ++nt) {
      u16x8 bf = *(const u16x8*)(Bs + (wc * 64 + nt * 16 + ln) * 40 + q * 8);
#pragma unroll
      for (int mt = 0; mt < 4; ++mt) acc[mt][nt] = mfma16(af[mt], bf, acc[mt][nt]);
    }
  }

#pragma unroll
  for (int mt = 0; mt < 4; ++mt) {
    const int rowb = m0 + wr * 64 + mt * 16 + q * 4;
#pragma unroll
    for (int nt = 0; nt < 4; ++nt) {
      const int col = n0 + wc * 64 + nt * 16 + ln;
      if (EPI == EPI_OUT && col >= 32) continue;
      const float bs = bias[col];
      const int ldc = (EPI == EPI_OUT) ? 32 : N;
#pragma unroll
      for (int r = 0; r < 4; ++r) {
        float v = acc[mt][nt][r] + bs;
        if (EPI == EPI_RELU) v = fmaxf(v, 0.f);
        C[(size_t)(rowb + r) * ldc + col] = f2bf(v);
      }
    }
  }
}

// ---------------------------------------------------------------------------
// Flash attention with alibi. qkv: [32768 tok x 1536] bf16 (q|k|v, 8 heads x 64)
// grid (seq*8, qt=4), block 256. Writes o [32768 x 512] bf16.
// ---------------------------------------------------------------------------
__global__ __launch_bounds__(256) void attn_k(const unsigned short* __restrict__ qkv,
                                              unsigned short* __restrict__ o) {
  __shared__ unsigned short Qs[128 * 72];
  __shared__ unsigned short Ks[64 * 72];
  __shared__ unsigned short Vts[64 * 72];  // transposed: [hd][key]
  __shared__ unsigned short Ps[128 * 72];
  const int tid = threadIdx.x;
  const int lane = tid & 63, w = tid >> 6, q = lane >> 4, ln = lane & 15;
  const int bh = blockIdx.x;
  const int seq = bh >> 3, h = bh & 7;
  const int qt = blockIdx.y;
  const size_t tokb = (size_t)seq * 512;
  const int qoff = h * 64, koff = 512 + h * 64, voff = 1024 + h * 64;
  const float slope = (h < 4) ? 1.0f : 0.5f;

#pragma unroll
  for (int p = 0; p < 4; ++p) {  // stage Q 128x64
    int c = p * 256 + tid;
    int row = c >> 3, cc = (c & 7) << 3;
    u16x8 v = *(const u16x8*)(qkv + (tokb + qt * 128 + row) * 1536 + qoff + cc);
    *(u16x8*)(Qs + row * 72 + cc) = v;
  }
  __syncthreads();
  u16x8 aq[2][2];
#pragma unroll
  for (int mt = 0; mt < 2; ++mt)
#pragma unroll
    for (int kc = 0; kc < 2; ++kc)
      aq[mt][kc] = *(const u16x8*)(Qs + (w * 32 + mt * 16 + ln) * 72 + kc * 32 + q * 8);

  float m_st[2][4], l_st[2][4];
  f32x4 o_acc[2][4];
#pragma unroll
  for (int mt = 0; mt < 2; ++mt)
#pragma unroll
    for (int r = 0; r < 4; ++r) { m_st[mt][r] = -1e30f; l_st[mt][r] = 0.f; }
#pragma unroll
  for (int mt = 0; mt < 2; ++mt)
#pragma unroll
    for (int ht = 0; ht < 4; ++ht) o_acc[mt][ht] = zero4();

  const int krow = tid >> 3, kcc = (tid & 7) << 3;
  const int vkey = tid >> 2, vhb = (tid & 3) << 4;

  for (int kt = 0; kt < 8; ++kt) {
    __syncthreads();
    {
      u16x8 v0 = *(const u16x8*)(qkv + (tokb + kt * 64 + krow) * 1536 + koff + kcc);
      u16x8 v1 = *(const u16x8*)(qkv + (tokb + kt * 64 + krow + 32) * 1536 + koff + kcc);
      *(u16x8*)(Ks + krow * 72 + kcc) = v0;
      *(u16x8*)(Ks + (krow + 32) * 72 + kcc) = v1;
      u16x8 w0 = *(const u16x8*)(qkv + (tokb + kt * 64 + vkey) * 1536 + voff + vhb);
      u16x8 w1 = *(const u16x8*)(qkv + (tokb + kt * 64 + vkey) * 1536 + voff + vhb + 8);
#pragma unroll
      for (int j = 0; j < 8; ++j) Vts[(vhb + j) * 72 + vkey] = w0[j];
#pragma unroll
      for (int j = 0; j < 8; ++j) Vts[(vhb + 8 + j) * 72 + vkey] = w1[j];
    }
    __syncthreads();

    f32x4 sacc[2][4];
#pragma unroll
    for (int mt = 0; mt < 2; ++mt)
#pragma unroll
      for (int nt = 0; nt < 4; ++nt) sacc[mt][nt] = zero4();
#pragma unroll
    for (int nt = 0; nt < 4; ++nt)
#pragma unroll
      for (int kc = 0; kc < 2; ++kc) {
        u16x8 bk = *(const u16x8*)(Ks + (nt * 16 + ln) * 72 + kc * 32 + q * 8);
#pragma unroll
        for (int mt = 0; mt < 2; ++mt) sacc[mt][nt] = mfma16(aq[mt][kc], bk, sacc[mt][nt]);
      }

    const float kbase = (float)(kt * 64 + ln);
#pragma unroll
    for (int mt = 0; mt < 2; ++mt) {
#pragma unroll
      for (int r = 0; r < 4; ++r) {
        const float qp = (float)(qt * 128 + w * 32 + mt * 16 + q * 4 + r);
        float mx = -1e30f;
#pragma unroll
        for (int nt = 0; nt < 4; ++nt) {
          float kp = kbase + (float)(nt * 16);
          float v = sacc[mt][nt][r] * 0.125f - slope * fabsf(qp - kp);
          sacc[mt][nt][r] = v;
          mx = fmaxf(mx, v);
        }
#pragma unroll
        for (int msk = 1; msk < 16; msk <<= 1) mx = fmaxf(mx, __shfl_xor(mx, msk, 64));
        const float mnew = fmaxf(m_st[mt][r], mx);
        const float alpha = exp2f((m_st[mt][r] - mnew) * 1.44269504f);
        m_st[mt][r] = mnew;
        float ssum = 0.f;
#pragma unroll
        for (int nt = 0; nt < 4; ++nt) {
          float p_ = exp2f((sacc[mt][nt][r] - mnew) * 1.44269504f);
          sacc[mt][nt][r] = p_;
          ssum += p_;
        }
#pragma unroll
        for (int msk = 1; msk < 16; msk <<= 1) ssum += __shfl_xor(ssum, msk, 64);
        l_st[mt][r] = l_st[mt][r] * alpha + ssum;
#pragma unroll
        for (int ht = 0; ht < 4; ++ht) o_acc[mt][ht][r] *= alpha;
        const int prow = w * 32 + mt * 16 + q * 4 + r;
#pragma unroll
        for (int nt = 0; nt < 4; ++nt) Ps[prow * 72 + nt * 16 + ln] = f2bf(sacc[mt][nt][r]);
      }
    }
    // P @ V  (Ps rows are wave-private; in-wave LDS ordering suffices)
#pragma unroll
    for (int kc = 0; kc < 2; ++kc) {
      u16x8 pa[2];
#pragma unroll
      for (int mt = 0; mt < 2; ++mt)
        pa[mt] = *(const u16x8*)(Ps + (w * 32 + mt * 16 + ln) * 72 + kc * 32 + q * 8);
#pragma unroll
      for (int ht = 0; ht < 4; ++ht) {
        u16x8 bv = *(const u16x8*)(Vts + (ht * 16 + ln) * 72 + kc * 32 + q * 8);
#pragma unroll
        for (int mt = 0; mt < 2; ++mt) o_acc[mt][ht] = mfma16(pa[mt], bv, o_acc[mt][ht]);
      }
    }
  }
#pragma unroll
  for (int mt = 0; mt < 2; ++mt)
#pragma unroll
    for (int ht = 0; ht < 4; ++ht)
#pragma unroll
      for (int r = 0; r < 4; ++r) {
        const int row = qt * 128 + w * 32 + mt * 16 + q * 4 + r;
        const float val = o_acc[mt][ht][r] / l_st[mt][r];
        o[(tokb + row) * 512 + h * 64 + ht * 16 + ln] = f2bf(val);
      }
}

// ---------------------------------------------------------------------------
// Fused residual + LayerNorm: out = LN(res + y) * g + b ; one wave per row (D=512)
// NOTE: out may alias res (in-place) -> no __restrict__ on those.
// ---------------------------------------------------------------------------
__global__ __launch_bounds__(256) void ln_k(const unsigned short* res,
                                            const unsigned short* __restrict__ y,
                                            const float* __restrict__ g,
                                            const float* __restrict__ b,
                                            unsigned short* out) {
  const int lane = threadIdx.x & 63, wv = threadIdx.x >> 6;
  const size_t row = (size_t)blockIdx.x * 4 + wv;
  const size_t base = row * 512 + lane * 8;
  u16x8 rv = *(const u16x8*)(res + base);
  u16x8 yv = *(const u16x8*)(y + base);
  float v[8];
  float s = 0.f, s2 = 0.f;
#pragma unroll
  for (int i = 0; i < 8; ++i) {
    v[i] = bf2f(rv[i]) + bf2f(yv[i]);
    s += v[i];
    s2 += v[i] * v[i];
  }
#pragma unroll
  for (int m = 1; m < 64; m <<= 1) {
    s += __shfl_xor(s, m, 64);
    s2 += __shfl_xor(s2, m, 64);
  }
  const float mean = s * (1.f / 512.f);
  const float var = s2 * (1.f / 512.f) - mean * mean;
  const float rstd = rsqrtf(var + 1e-5f);
  const int c = lane * 8;
  u16x8 ov;
#pragma unroll
  for (int i = 0; i < 8; ++i) ov[i] = f2bf((v[i] - mean) * rstd * g[c + i] + b[c + i]);
  *(u16x8*)(out + base) = ov;
}

// ---------------------------------------------------------------------------
// Weight transpose fp32 (Kin x Nin) -> bf16 (Nout x Kout), zero-padded.
// ---------------------------------------------------------------------------
__global__ __launch_bounds__(256) void transpose_w(const float* __restrict__ in,
                                                   unsigned short* __restrict__ out,
                                                   int Kin, int Nin, int Kout, int Nout) {
  __shared__ float tile[32][33];
  const int nb = blockIdx.x * 32, kb = blockIdx.y * 32;
  const int tx = threadIdx.x & 31, ty = threadIdx.x >> 5;
#pragma unroll
  for (int i = 0; i < 32; i += 8) {
    int k = kb + ty + i, n = nb + tx;
    tile[ty + i][tx] = (k < Kin && n < Nin) ? in[(size_t)k * Nin + n] : 0.f;
  }
  __syncthreads();
#pragma unroll
  for (int i = 0; i < 32; i += 8) {
    int n = nb + ty + i, k = kb + tx;
    if (n < Nout && k < Kout) out[(size_t)n * Kout + k] = f2bf(tile[tx][ty + i]);
  }
}

// x (64 x 20480) fp32 -> xpad (65536 tok x 32) bf16 (K padded 20->32)
__global__ __launch_bounds__(256) void xpad_k(const float* __restrict__ x,
                                              unsigned short* __restrict__ xp) {
  const int idx = blockIdx.x * 256 + threadIdx.x;  // 65536*32
  const int tok = idx >> 5, k = idx & 31;
  const int seq = tok >> 9, s = tok & 511;
  const int hf = seq >> 6, b = seq & 63;
  float v = 0.f;
  if (k < 20) v = x[(size_t)b * 20480 + hf * 10240 + s * 20 + k];
  xp[idx] = f2bf(v);
}

// Head d1: h(64 x 32768) @ d1_W(32768 x 256); split-K partials, deterministic.
__global__ __launch_bounds__(256) void d1_part(const unsigned short* __restrict__ enc,
                                               const float* __restrict__ W,
                                               float* __restrict__ pz) {
  __shared__ unsigned short hs[4096];
  const int m = blockIdx.y, sl = blockIdx.x;
  const int kb = sl * 4096;
  for (int i = 0; i < 16; ++i) {
    int k = kb + i * 256 + threadIdx.x;
    int hf = k >> 14, j = k & 16383;
    hs[i * 256 + threadIdx.x] = enc[(size_t)(hf * 64 + m) * 16384 + j];
  }
  __syncthreads();
  const int n = threadIdx.x;
  float acc = 0.f;
#pragma unroll 8
  for (int kk = 0; kk < 4096; ++kk) acc += bf2f(hs[kk]) * W[(size_t)(kb + kk) * 256 + n];
  pz[(size_t)(sl * 64 + m) * 256 + n] = acc;
}

__global__ __launch_bounds__(256) void d1_fin(const float* __restrict__ pz,
                                              const float* __restrict__ d1b,
                                              const float* __restrict__ g,
                                              const float* __restrict__ b,
                                              const float* __restrict__ mm,
                                              const float* __restrict__ vv,
                                              float* __restrict__ h1) {
  const int m = blockIdx.x, n = threadIdx.x;
  float a = d1b[n];
  for (int sl = 0; sl < 8; ++sl) a += pz[(size_t)(sl * 64 + m) * 256 + n];
  a = fmaxf(a, 0.f);
  a = (a - mm[n]) * rsqrtf(vv[n] + 1e-5f) * g[n] + b[n];
  h1[m * 256 + n] = a;
}

__global__ __launch_bounds__(128) void d2_k(const float* __restrict__ h1,
                                            const float* __restrict__ W,
                                            const float* __restrict__ bb,
                                            const float* __restrict__ g,
                                            const float* __restrict__ b,
                                            const float* __restrict__ mm,
                                            const float* __restrict__ vv,
                                            float* __restrict__ h2) {
  __shared__ float hs[256];
  const int m = blockIdx.x, n = threadIdx.x;
  hs[n] = h1[m * 256 + n];
  hs[n + 128] = h1[m * 256 + n + 128];
  __syncthreads();
  float a = bb[n];
#pragma unroll 8
  for (int k = 0; k < 256; ++k) a += hs[k] * W[k * 128 + n];
  a = fmaxf(a, 0.f);
  a = (a - mm[n]) * rsqrtf(vv[n] + 1e-5f) * g[n] + b[n];
  h2[m * 128 + n] = a;
}

__global__ __launch_bounds__(64) void fin_k(const float* __restrict__ h2,
                                            const float* __restrict__ W,
                                            const float* __restrict__ fb,
                                            float* __restrict__ out) {
  const int m = threadIdx.x;
  float a = fb[0];
#pragma unroll 8
  for (int k = 0; k < 128; ++k) a += h2[m * 128 + k] * W[k];
  out[m] = a;
}

// ---------------------------------------------------------------------------
extern "C" void kernel_launch(void* const* d_in, const int* in_sizes, int n_in,
                              void* d_out, int out_size, void* d_ws, size_t ws_size,
                              hipStream_t stream) {
  const float* x      = (const float*)d_in[0];
  const float* in_W   = (const float*)d_in[1];
  const float* in_b   = (const float*)d_in[2];
  const float* qkv_W  = (const float*)d_in[3];
  const float* qkv_b  = (const float*)d_in[4];
  const float* ln1_g  = (const float*)d_in[5];
  const float* ln1_b  = (const float*)d_in[6];
  const float* ffn_W1 = (const float*)d_in[7];
  const float* ffn_b1 = (const float*)d_in[8];
  const float* ffn_W2 = (const float*)d_in[9];
  const float* ffn_b2 = (const float*)d_in[10];
  const float* ln2_g  = (const float*)d_in[11];
  const float* ln2_b  = (const float*)d_in[12];
  const float* out_W  = (const float*)d_in[13];
  const float* out_b  = (const float*)d_in[14];
  const float* d1W    = (const float*)d_in[15];
  const float* d1b    = (const float*)d_in[16];
  const float* bn1g   = (const float*)d_in[17];
  const float* bn1b   = (const float*)d_in[18];
  const float* bn1m   = (const float*)d_in[19];
  const float* bn1v   = (const float*)d_in[20];
  const float* d2W    = (const float*)d_in[21];
  const float* d2b    = (const float*)d_in[22];
  const float* bn2g   = (const float*)d_in[23];
  const float* bn2b   = (const float*)d_in[24];
  const float* bn2m   = (const float*)d_in[25];
  const float* bn2v   = (const float*)d_in[26];
  const float* finW   = (const float*)d_in[27];
  const float* finb   = (const float*)d_in[28];
  (void)in_sizes; (void)n_in; (void)out_size; (void)ws_size;

  char* ws = (char*)d_ws;
  size_t off = 0;
  auto alloc = [&](size_t bytes) {
    char* p = ws + off;
    off += (bytes + 255) & ~(size_t)255;
    return p;
  };
  unsigned short* t     = (unsigned short*)alloc(32768ull * 512 * 2);   //  33.5 MB
  unsigned short* big   = (unsigned short*)alloc(32768ull * 2048 * 2);  // 134 MB (qkv / f1)
  unsigned short* ob    = (unsigned short*)alloc(32768ull * 512 * 2);   //  33.5 MB (o / y)
  unsigned short* xpad  = (unsigned short*)alloc(65536ull * 32 * 2);
  unsigned short* enc   = (unsigned short*)alloc(65536ull * 32 * 2);
  unsigned short* inWt  = (unsigned short*)alloc(512ull * 32 * 2);
  unsigned short* qkvWt = (unsigned short*)alloc(4ull * 1536 * 512 * 2);
  unsigned short* f1Wt  = (unsigned short*)alloc(4ull * 2048 * 512 * 2);
  unsigned short* f2Wt  = (unsigned short*)alloc(4ull * 512 * 2048 * 2);
  unsigned short* outWt = (unsigned short*)alloc(128ull * 512 * 2);
  float* pz = (float*)alloc(8ull * 64 * 256 * 4);
  float* h1 = (float*)alloc(64ull * 256 * 4);
  float* h2 = (float*)alloc(64ull * 128 * 4);

  // weight prep (per-call: ws/d_in are re-poisoned/restored each launch)
  xpad_k<<<8192, 256, 0, stream>>>(x, xpad);
  transpose_w<<<dim3(16, 1), 256, 0, stream>>>(in_W, inWt, 20, 512, 32, 512);
  transpose_w<<<dim3(4, 16), 256, 0, stream>>>(out_W, outWt, 512, 32, 512, 128);
  for (int l = 0; l < 4; ++l) {
    transpose_w<<<dim3(48, 16), 256, 0, stream>>>(qkv_W + (size_t)l * 512 * 1536,
                                                  qkvWt + (size_t)l * 1536 * 512, 512, 1536, 512, 1536);
    transpose_w<<<dim3(64, 16), 256, 0, stream>>>(ffn_W1 + (size_t)l * 512 * 2048,
                                                  f1Wt + (size_t)l * 2048 * 512, 512, 2048, 512, 2048);
    transpose_w<<<dim3(16, 64), 256, 0, stream>>>(ffn_W2 + (size_t)l * 2048 * 512,
                                                  f2Wt + (size_t)l * 512 * 2048, 2048, 512, 2048, 512);
  }

  for (int hf = 0; hf < 2; ++hf) {
    gemm_k<EPI_BIAS><<<dim3(4, 256), 256, 0, stream>>>(xpad + (size_t)hf * 32768 * 32, inWt, in_b, t, 512, 32);
    for (int l = 0; l < 4; ++l) {
      gemm_k<EPI_BIAS><<<dim3(12, 256), 256, 0, stream>>>(t, qkvWt + (size_t)l * 1536 * 512,
                                                          qkv_b + l * 1536, big, 1536, 512);
      attn_k<<<dim3(512, 4), 256, 0, stream>>>(big, ob);
      ln_k<<<8192, 256, 0, stream>>>(t, ob, ln1_g + l * 512, ln1_b + l * 512, t);
      gemm_k<EPI_RELU><<<dim3(16, 256), 256, 0, stream>>>(t, f1Wt + (size_t)l * 2048 * 512,
                                                          ffn_b1 + l * 2048, big, 2048, 512);
      gemm_k<EPI_BIAS><<<dim3(4, 256), 256, 0, stream>>>(big, f2Wt + (size_t)l * 512 * 2048,
                                                         ffn_b2 + l * 512, ob, 512, 2048);
      ln_k<<<8192, 256, 0, stream>>>(t, ob, ln2_g + l * 512, ln2_b + l * 512, t);
    }
    gemm_k<EPI_OUT><<<dim3(1, 256), 256, 0, stream>>>(t, outWt, out_b,
                                                      enc + (size_t)hf * 32768 * 32, 128, 512);
  }

  d1_part<<<dim3(8, 64), 256, 0, stream>>>(enc, d1W, pz);
  d1_fin<<<64, 256, 0, stream>>>(pz, d1b, bn1g, bn1b, bn1m, bn1v, h1);
  d2_k<<<64, 128, 0, stream>>>(h1, d2W, d2b, bn2g, bn2b, bn2m, bn2v, h2);
  fin_k<<<1, 64, 0, stream>>>(h2, finW, finb, (float*)d_out);
}

// Round 2
// 4266.858 us; speedup vs baseline: 1.0903x; 1.0903x over previous
//
#include <hip/hip_runtime.h>

#define DEV __device__ __forceinline__

using bf16x8 = __attribute__((ext_vector_type(8))) __bf16;
using f32x4  = __attribute__((ext_vector_type(4))) float;
using u16x8  = __attribute__((ext_vector_type(8))) unsigned short;

DEV unsigned short f2bf(float f) {
  unsigned u = __builtin_bit_cast(unsigned, f);
  u += 0x7fffu + ((u >> 16) & 1u);
  return (unsigned short)(u >> 16);
}
DEV float bf2f(unsigned short h) {
  unsigned u = ((unsigned)h) << 16;
  return __builtin_bit_cast(float, u);
}
DEV f32x4 mfma16(u16x8 a, u16x8 b, f32x4 c) {
  return __builtin_amdgcn_mfma_f32_16x16x32_bf16(
      __builtin_bit_cast(bf16x8, a), __builtin_bit_cast(bf16x8, b), c, 0, 0, 0);
}
DEV f32x4 zero4() { f32x4 z = {0.f, 0.f, 0.f, 0.f}; return z; }

// async global->LDS, 16B per lane. lds dest = wave-uniform base + lane*16.
DEV void glds16(const unsigned short* g, unsigned short* l) {
  __builtin_amdgcn_global_load_lds(
      (const __attribute__((address_space(1))) unsigned int*)g,
      (__attribute__((address_space(3))) unsigned int*)l, 16, 0, 0);
}

// ---------------------------------------------------------------------------
// m97-style bf16 MFMA GEMM: C[M x N] = A[M x K] * Bt[N x K]^T + bias.
// 128x128 tile, BK=32, global_load_lds width-16 staging, UNPADDED LDS
// (contiguity required by global_load_lds; stride 64B -> 2-way b128 aliasing
//  which is free per m136).
// ---------------------------------------------------------------------------
enum { EPI_BIAS = 0, EPI_RELU = 1, EPI_OUT = 2 };

template <int EPI>
__global__ __launch_bounds__(256) void gemm_k(
    const unsigned short* __restrict__ A, const unsigned short* __restrict__ Bt,
    const float* __restrict__ bias, unsigned short* __restrict__ C, int N, int K) {
  __shared__ unsigned short As[128 * 32];  // 8 KB, row-major, no pad
  __shared__ unsigned short Bs[128 * 32];
  const int tid = threadIdx.x;
  const int lane = tid & 63, wv = tid >> 6;
  const int q = lane >> 4, ln = lane & 15;
  const int wr = wv >> 1, wc = wv & 1;
  const int m0 = blockIdx.y << 7, n0 = blockIdx.x << 7;

  f32x4 acc[4][4];
#pragma unroll
  for (int i = 0; i < 4; ++i)
#pragma unroll
    for (int j = 0; j < 4; ++j) acc[i][j] = zero4();

  // staging: chunk id = tid (issue 0) / 256+tid (issue 1); row=ch>>2, col8=(ch&3)*8
  const int r0 = tid >> 2, c0 = (tid & 3) << 3;
  const unsigned short* Ap0 = A + (size_t)(m0 + r0) * K + c0;
  const unsigned short* Ap1 = A + (size_t)(m0 + r0 + 64) * K + c0;
  const unsigned short* Bp0 = Bt + (size_t)(n0 + r0) * K + c0;
  const unsigned short* Bp1 = Bt + (size_t)(n0 + r0 + 64) * K + c0;
  unsigned short* AsL0 = As + wv * 512;         // wave-uniform LDS bases
  unsigned short* AsL1 = As + 2048 + wv * 512;  // (chunk*8 shorts = chunk*16 B)
  unsigned short* BsL0 = Bs + wv * 512;
  unsigned short* BsL1 = Bs + 2048 + wv * 512;

  for (int kb = 0; kb < K; kb += 32) {
    __syncthreads();  // WAR: prior ds_reads done before overwrite
    glds16(Ap0 + kb, AsL0);
    glds16(Ap1 + kb, AsL1);
    glds16(Bp0 + kb, BsL0);
    glds16(Bp1 + kb, BsL1);
    __syncthreads();  // barrier drains vmcnt -> tiles visible
    u16x8 af[4];
#pragma unroll
    for (int mt = 0; mt < 4; ++mt)
      af[mt] = *(const u16x8*)(As + (wr * 64 + mt * 16 + ln) * 32 + q * 8);
#pragma unroll
    for (int nt = 0; nt < 4; ++nt) {
      u16x8 bf = *(const u16x8*)(Bs + (wc * 64 + nt * 16 + ln) * 32 + q * 8);
#pragma unroll
      for (int mt = 0; mt < 4; ++mt) acc[mt][nt] = mfma16(af[mt], bf, acc[mt][nt]);
    }
  }

#pragma unroll
  for (int mt = 0; mt < 4; ++mt) {
    const int rowb = m0 + wr * 64 + mt * 16 + q * 4;
#pragma unroll
    for (int nt = 0; nt < 4; ++nt) {
      const int col = n0 + wc * 64 + nt * 16 + ln;
      if (EPI == EPI_OUT && col >= 32) continue;
      const float bs = bias[col];
      const int ldc = (EPI == EPI_OUT) ? 32 : N;
#pragma unroll
      for (int r = 0; r < 4; ++r) {
        float v = acc[mt][nt][r] + bs;
        if (EPI == EPI_RELU) v = fmaxf(v, 0.f);
        C[(size_t)(rowb + r) * ldc + col] = f2bf(v);
      }
    }
  }
}

// ---------------------------------------------------------------------------
// Flash attention with alibi. qkv: [32768 tok x 1536] bf16 (q|k|v, 8 heads x 64)
// grid (seq*8, qt=4), block 256. Writes o [32768 x 512] bf16.
// ---------------------------------------------------------------------------
__global__ __launch_bounds__(256) void attn_k(const unsigned short* __restrict__ qkv,
                                              unsigned short* __restrict__ o) {
  __shared__ unsigned short Qs[128 * 72];
  __shared__ unsigned short Ks[64 * 72];
  __shared__ unsigned short Vts[64 * 72];  // transposed: [hd][key]
  __shared__ unsigned short Ps[128 * 72];
  const int tid = threadIdx.x;
  const int lane = tid & 63, w = tid >> 6, q = lane >> 4, ln = lane & 15;
  const int bh = blockIdx.x;
  const int seq = bh >> 3, h = bh & 7;
  const int qt = blockIdx.y;
  const size_t tokb = (size_t)seq * 512;
  const int qoff = h * 64, koff = 512 + h * 64, voff = 1024 + h * 64;
  const float slope = (h < 4) ? 1.0f : 0.5f;

#pragma unroll
  for (int p = 0; p < 4; ++p) {  // stage Q 128x64
    int c = p * 256 + tid;
    int row = c >> 3, cc = (c & 7) << 3;
    u16x8 v = *(const u16x8*)(qkv + (tokb + qt * 128 + row) * 1536 + qoff + cc);
    *(u16x8*)(Qs + row * 72 + cc) = v;
  }
  __syncthreads();
  u16x8 aq[2][2];
#pragma unroll
  for (int mt = 0; mt < 2; ++mt)
#pragma unroll
    for (int kc = 0; kc < 2; ++kc)
      aq[mt][kc] = *(const u16x8*)(Qs + (w * 32 + mt * 16 + ln) * 72 + kc * 32 + q * 8);

  float m_st[2][4], l_st[2][4];
  f32x4 o_acc[2][4];
#pragma unroll
  for (int mt = 0; mt < 2; ++mt)
#pragma unroll
    for (int r = 0; r < 4; ++r) { m_st[mt][r] = -1e30f; l_st[mt][r] = 0.f; }
#pragma unroll
  for (int mt = 0; mt < 2; ++mt)
#pragma unroll
    for (int ht = 0; ht < 4; ++ht) o_acc[mt][ht] = zero4();

  const int krow = tid >> 3, kcc = (tid & 7) << 3;
  const int vkey = tid >> 2, vhb = (tid & 3) << 4;

  for (int kt = 0; kt < 8; ++kt) {
    __syncthreads();
    {
      u16x8 v0 = *(const u16x8*)(qkv + (tokb + kt * 64 + krow) * 1536 + koff + kcc);
      u16x8 v1 = *(const u16x8*)(qkv + (tokb + kt * 64 + krow + 32) * 1536 + koff + kcc);
      *(u16x8*)(Ks + krow * 72 + kcc) = v0;
      *(u16x8*)(Ks + (krow + 32) * 72 + kcc) = v1;
      u16x8 w0 = *(const u16x8*)(qkv + (tokb + kt * 64 + vkey) * 1536 + voff + vhb);
      u16x8 w1 = *(const u16x8*)(qkv + (tokb + kt * 64 + vkey) * 1536 + voff + vhb + 8);
#pragma unroll
      for (int j = 0; j < 8; ++j) Vts[(vhb + j) * 72 + vkey] = w0[j];
#pragma unroll
      for (int j = 0; j < 8; ++j) Vts[(vhb + 8 + j) * 72 + vkey] = w1[j];
    }
    __syncthreads();

    f32x4 sacc[2][4];
#pragma unroll
    for (int mt = 0; mt < 2; ++mt)
#pragma unroll
      for (int nt = 0; nt < 4; ++nt) sacc[mt][nt] = zero4();
#pragma unroll
    for (int nt = 0; nt < 4; ++nt)
#pragma unroll
      for (int kc = 0; kc < 2; ++kc) {
        u16x8 bk = *(const u16x8*)(Ks + (nt * 16 + ln) * 72 + kc * 32 + q * 8);
#pragma unroll
        for (int mt = 0; mt < 2; ++mt) sacc[mt][nt] = mfma16(aq[mt][kc], bk, sacc[mt][nt]);
      }

    const float kbase = (float)(kt * 64 + ln);
#pragma unroll
    for (int mt = 0; mt < 2; ++mt) {
#pragma unroll
      for (int r = 0; r < 4; ++r) {
        const float qp = (float)(qt * 128 + w * 32 + mt * 16 + q * 4 + r);
        float mx = -1e30f;
#pragma unroll
        for (int nt = 0; nt < 4; ++nt) {
          float kp = kbase + (float)(nt * 16);
          float v = sacc[mt][nt][r] * 0.125f - slope * fabsf(qp - kp);
          sacc[mt][nt][r] = v;
          mx = fmaxf(mx, v);
        }
#pragma unroll
        for (int msk = 1; msk < 16; msk <<= 1) mx = fmaxf(mx, __shfl_xor(mx, msk, 64));
        const float mnew = fmaxf(m_st[mt][r], mx);
        const float alpha = exp2f((m_st[mt][r] - mnew) * 1.44269504f);
        m_st[mt][r] = mnew;
        float ssum = 0.f;
#pragma unroll
        for (int nt = 0; nt < 4; ++nt) {
          float p_ = exp2f((sacc[mt][nt][r] - mnew) * 1.44269504f);
          sacc[mt][nt][r] = p_;
          ssum += p_;
        }
#pragma unroll
        for (int msk = 1; msk < 16; msk <<= 1) ssum += __shfl_xor(ssum, msk, 64);
        l_st[mt][r] = l_st[mt][r] * alpha + ssum;
#pragma unroll
        for (int ht = 0; ht < 4; ++ht) o_acc[mt][ht][r] *= alpha;
        const int prow = w * 32 + mt * 16 + q * 4 + r;
#pragma unroll
        for (int nt = 0; nt < 4; ++nt) Ps[prow * 72 + nt * 16 + ln] = f2bf(sacc[mt][nt][r]);
      }
    }
    // P @ V  (Ps rows are wave-private; in-wave LDS ordering suffices)
#pragma unroll
    for (int kc = 0; kc < 2; ++kc) {
      u16x8 pa[2];
#pragma unroll
      for (int mt = 0; mt < 2; ++mt)
        pa[mt] = *(const u16x8*)(Ps + (w * 32 + mt * 16 + ln) * 72 + kc * 32 + q * 8);
#pragma unroll
      for (int ht = 0; ht < 4; ++ht) {
        u16x8 bv = *(const u16x8*)(Vts + (ht * 16 + ln) * 72 + kc * 32 + q * 8);
#pragma unroll
        for (int mt = 0; mt < 2; ++mt) o_acc[mt][ht] = mfma16(pa[mt], bv, o_acc[mt][ht]);
      }
    }
  }
#pragma unroll
  for (int mt = 0; mt < 2; ++mt)
#pragma unroll
    for (int ht = 0; ht < 4; ++ht)
#pragma unroll
      for (int r = 0; r < 4; ++r) {
        const int row = qt * 128 + w * 32 + mt * 16 + q * 4 + r;
        const float val = o_acc[mt][ht][r] / l_st[mt][r];
        o[(tokb + row) * 512 + h * 64 + ht * 16 + ln] = f2bf(val);
      }
}

// ---------------------------------------------------------------------------
// Fused residual + LayerNorm (in-place capable)
// ---------------------------------------------------------------------------
__global__ __launch_bounds__(256) void ln_k(const unsigned short* res,
                                            const unsigned short* __restrict__ y,
                                            const float* __restrict__ g,
                                            const float* __restrict__ b,
                                            unsigned short* out) {
  const int lane = threadIdx.x & 63, wv = threadIdx.x >> 6;
  const size_t row = (size_t)blockIdx.x * 4 + wv;
  const size_t base = row * 512 + lane * 8;
  u16x8 rv = *(const u16x8*)(res + base);
  u16x8 yv = *(const u16x8*)(y + base);
  float v[8];
  float s = 0.f, s2 = 0.f;
#pragma unroll
  for (int i = 0; i < 8; ++i) {
    v[i] = bf2f(rv[i]) + bf2f(yv[i]);
    s += v[i];
    s2 += v[i] * v[i];
  }
#pragma unroll
  for (int m = 1; m < 64; m <<= 1) {
    s += __shfl_xor(s, m, 64);
    s2 += __shfl_xor(s2, m, 64);
  }
  const float mean = s * (1.f / 512.f);
  const float var = s2 * (1.f / 512.f) - mean * mean;
  const float rstd = rsqrtf(var + 1e-5f);
  const int c = lane * 8;
  u16x8 ov;
#pragma unroll
  for (int i = 0; i < 8; ++i) ov[i] = f2bf((v[i] - mean) * rstd * g[c + i] + b[c + i]);
  *(u16x8*)(out + base) = ov;
}

// ---------------------------------------------------------------------------
// Weight transpose fp32 (Kin x Nin) -> bf16 (Nout x Kout), zero-padded.
// ---------------------------------------------------------------------------
__global__ __launch_bounds__(256) void transpose_w(const float* __restrict__ in,
                                                   unsigned short* __restrict__ out,
                                                   int Kin, int Nin, int Kout, int Nout) {
  __shared__ float tile[32][33];
  const int nb = blockIdx.x * 32, kb = blockIdx.y * 32;
  const int tx = threadIdx.x & 31, ty = threadIdx.x >> 5;
#pragma unroll
  for (int i = 0; i < 32; i += 8) {
    int k = kb + ty + i, n = nb + tx;
    tile[ty + i][tx] = (k < Kin && n < Nin) ? in[(size_t)k * Nin + n] : 0.f;
  }
  __syncthreads();
#pragma unroll
  for (int i = 0; i < 32; i += 8) {
    int n = nb + ty + i, k = kb + tx;
    if (n < Nout && k < Kout) out[(size_t)n * Kout + k] = f2bf(tile[tx][ty + i]);
  }
}

// x (64 x 20480) fp32 -> xpad (65536 tok x 32) bf16 (K padded 20->32)
__global__ __launch_bounds__(256) void xpad_k(const float* __restrict__ x,
                                              unsigned short* __restrict__ xp) {
  const int idx = blockIdx.x * 256 + threadIdx.x;  // 65536*32
  const int tok = idx >> 5, k = idx & 31;
  const int seq = tok >> 9, s = tok & 511;
  const int hf = seq >> 6, b = seq & 63;
  float v = 0.f;
  if (k < 20) v = x[(size_t)b * 20480 + hf * 10240 + s * 20 + k];
  xp[idx] = f2bf(v);
}

// ---------------------------------------------------------------------------
// Head d1: h(64 x 32768) @ d1_W(32768 x 256). 256 K-slices of 128; W read
// exactly once; enc slice staged as fp32 in LDS (broadcast reads); acc[64].
// ---------------------------------------------------------------------------
__global__ __launch_bounds__(256) void d1_part(const unsigned short* __restrict__ enc,
                                               const float* __restrict__ W,
                                               float* __restrict__ pz) {
  __shared__ float ef[64 * 128];  // 32 KB
  const int tid = threadIdx.x;
  const int kb = blockIdx.x * 128;  // 128 % 16384 boundaries align: one hf per block
  const int hf = kb >> 14;
  const int j0 = kb & 16383;
  {
    const int m = tid >> 2, c = (tid & 3) * 32;
    const unsigned short* src = enc + (size_t)hf * 1048576 + (size_t)m * 16384 + j0 + c;
#pragma unroll
    for (int i = 0; i < 4; ++i) {
      u16x8 v = *(const u16x8*)(src + i * 8);
#pragma unroll
      for (int jj = 0; jj < 8; ++jj) ef[m * 128 + c + i * 8 + jj] = bf2f(v[jj]);
    }
  }
  __syncthreads();
  const int n = tid;
  float acc[64];
#pragma unroll
  for (int m = 0; m < 64; ++m) acc[m] = 0.f;
  for (int kc = 0; kc < 128; kc += 4) {
    const float w0 = W[(size_t)(kb + kc) * 256 + n];
    const float w1 = W[(size_t)(kb + kc + 1) * 256 + n];
    const float w2 = W[(size_t)(kb + kc + 2) * 256 + n];
    const float w3 = W[(size_t)(kb + kc + 3) * 256 + n];
#pragma unroll
    for (int m = 0; m < 64; ++m) {
      const f32x4 e = *(const f32x4*)(ef + m * 128 + kc);
      acc[m] += e[0] * w0 + e[1] * w1 + e[2] * w2 + e[3] * w3;
    }
  }
#pragma unroll
  for (int m = 0; m < 64; ++m)
    pz[(size_t)(blockIdx.x * 64 + m) * 256 + n] = acc[m];
}

__global__ __launch_bounds__(256) void d1_fin(const float* __restrict__ pz,
                                              const float* __restrict__ d1b,
                                              const float* __restrict__ g,
                                              const float* __restrict__ b,
                                              const float* __restrict__ mm,
                                              const float* __restrict__ vv,
                                              float* __restrict__ h1) {
  const int m = blockIdx.x, n = threadIdx.x;
  float a = d1b[n];
  for (int sl = 0; sl < 256; ++sl) a += pz[(size_t)(sl * 64 + m) * 256 + n];
  a = fmaxf(a, 0.f);
  a = (a - mm[n]) * rsqrtf(vv[n] + 1e-5f) * g[n] + b[n];
  h1[m * 256 + n] = a;
}

__global__ __launch_bounds__(128) void d2_k(const float* __restrict__ h1,
                                            const float* __restrict__ W,
                                            const float* __restrict__ bb,
                                            const float* __restrict__ g,
                                            const float* __restrict__ b,
                                            const float* __restrict__ mm,
                                            const float* __restrict__ vv,
                                            float* __restrict__ h2) {
  __shared__ float hs[256];
  const int m = blockIdx.x, n = threadIdx.x;
  hs[n] = h1[m * 256 + n];
  hs[n + 128] = h1[m * 256 + n + 128];
  __syncthreads();
  float a = bb[n];
#pragma unroll 8
  for (int k = 0; k < 256; ++k) a += hs[k] * W[k * 128 + n];
  a = fmaxf(a, 0.f);
  a = (a - mm[n]) * rsqrtf(vv[n] + 1e-5f) * g[n] + b[n];
  h2[m * 128 + n] = a;
}

__global__ __launch_bounds__(64) void fin_k(const float* __restrict__ h2,
                                            const float* __restrict__ W,
                                            const float* __restrict__ fb,
                                            float* __restrict__ out) {
  const int m = threadIdx.x;
  float a = fb[0];
#pragma unroll 8
  for (int k = 0; k < 128; ++k) a += h2[m * 128 + k] * W[k];
  out[m] = a;
}

// ---------------------------------------------------------------------------
extern "C" void kernel_launch(void* const* d_in, const int* in_sizes, int n_in,
                              void* d_out, int out_size, void* d_ws, size_t ws_size,
                              hipStream_t stream) {
  const float* x      = (const float*)d_in[0];
  const float* in_W   = (const float*)d_in[1];
  const float* in_b   = (const float*)d_in[2];
  const float* qkv_W  = (const float*)d_in[3];
  const float* qkv_b  = (const float*)d_in[4];
  const float* ln1_g  = (const float*)d_in[5];
  const float* ln1_b  = (const float*)d_in[6];
  const float* ffn_W1 = (const float*)d_in[7];
  const float* ffn_b1 = (const float*)d_in[8];
  const float* ffn_W2 = (const float*)d_in[9];
  const float* ffn_b2 = (const float*)d_in[10];
  const float* ln2_g  = (const float*)d_in[11];
  const float* ln2_b  = (const float*)d_in[12];
  const float* out_W  = (const float*)d_in[13];
  const float* out_b  = (const float*)d_in[14];
  const float* d1W    = (const float*)d_in[15];
  const float* d1b    = (const float*)d_in[16];
  const float* bn1g   = (const float*)d_in[17];
  const float* bn1b   = (const float*)d_in[18];
  const float* bn1m   = (const float*)d_in[19];
  const float* bn1v   = (const float*)d_in[20];
  const float* d2W    = (const float*)d_in[21];
  const float* d2b    = (const float*)d_in[22];
  const float* bn2g   = (const float*)d_in[23];
  const float* bn2b   = (const float*)d_in[24];
  const float* bn2m   = (const float*)d_in[25];
  const float* bn2v   = (const float*)d_in[26];
  const float* finW   = (const float*)d_in[27];
  const float* finb   = (const float*)d_in[28];
  (void)in_sizes; (void)n_in; (void)out_size; (void)ws_size;

  char* ws = (char*)d_ws;
  size_t off = 0;
  auto alloc = [&](size_t bytes) {
    char* p = ws + off;
    off += (bytes + 255) & ~(size_t)255;
    return p;
  };
  unsigned short* t     = (unsigned short*)alloc(32768ull * 512 * 2);   //  33.5 MB
  unsigned short* big   = (unsigned short*)alloc(32768ull * 2048 * 2);  // 134 MB (qkv / f1 / pz)
  unsigned short* ob    = (unsigned short*)alloc(32768ull * 512 * 2);   //  33.5 MB (o / y)
  unsigned short* xpad  = (unsigned short*)alloc(65536ull * 32 * 2);
  unsigned short* enc   = (unsigned short*)alloc(65536ull * 32 * 2);
  unsigned short* inWt  = (unsigned short*)alloc(512ull * 32 * 2);
  unsigned short* qkvWt = (unsigned short*)alloc(4ull * 1536 * 512 * 2);
  unsigned short* f1Wt  = (unsigned short*)alloc(4ull * 2048 * 512 * 2);
  unsigned short* f2Wt  = (unsigned short*)alloc(4ull * 512 * 2048 * 2);
  unsigned short* outWt = (unsigned short*)alloc(128ull * 512 * 2);
  float* h1 = (float*)alloc(64ull * 256 * 4);
  float* h2 = (float*)alloc(64ull * 128 * 4);
  float* pz = (float*)big;  // 16.8 MB partials; `big` is free by d1 time

  // weight prep (per-call: ws/d_in are re-poisoned/restored each launch)
  xpad_k<<<8192, 256, 0, stream>>>(x, xpad);
  transpose_w<<<dim3(16, 1), 256, 0, stream>>>(in_W, inWt, 20, 512, 32, 512);
  transpose_w<<<dim3(4, 16), 256, 0, stream>>>(out_W, outWt, 512, 32, 512, 128);
  for (int l = 0; l < 4; ++l) {
    transpose_w<<<dim3(48, 16), 256, 0, stream>>>(qkv_W + (size_t)l * 512 * 1536,
                                                  qkvWt + (size_t)l * 1536 * 512, 512, 1536, 512, 1536);
    transpose_w<<<dim3(64, 16), 256, 0, stream>>>(ffn_W1 + (size_t)l * 512 * 2048,
                                                  f1Wt + (size_t)l * 2048 * 512, 512, 2048, 512, 2048);
    transpose_w<<<dim3(16, 64), 256, 0, stream>>>(ffn_W2 + (size_t)l * 2048 * 512,
                                                  f2Wt + (size_t)l * 512 * 2048, 2048, 512, 2048, 512);
  }

  for (int hf = 0; hf < 2; ++hf) {
    gemm_k<EPI_BIAS><<<dim3(4, 256), 256, 0, stream>>>(xpad + (size_t)hf * 32768 * 32, inWt, in_b, t, 512, 32);
    for (int l = 0; l < 4; ++l) {
      gemm_k<EPI_BIAS><<<dim3(12, 256), 256, 0, stream>>>(t, qkvWt + (size_t)l * 1536 * 512,
                                                          qkv_b + l * 1536, big, 1536, 512);
      attn_k<<<dim3(512, 4), 256, 0, stream>>>(big, ob);
      ln_k<<<8192, 256, 0, stream>>>(t, ob, ln1_g + l * 512, ln1_b + l * 512, t);
      gemm_k<EPI_RELU><<<dim3(16, 256), 256, 0, stream>>>(t, f1Wt + (size_t)l * 2048 * 512,
                                                          ffn_b1 + l * 2048, big, 2048, 512);
      gemm_k<EPI_BIAS><<<dim3(4, 256), 256, 0, stream>>>(big, f2Wt + (size_t)l * 512 * 2048,
                                                         ffn_b2 + l * 512, ob, 512, 2048);
      ln_k<<<8192, 256, 0, stream>>>(t, ob, ln2_g + l * 512, ln2_b + l * 512, t);
    }
    gemm_k<EPI_OUT><<<dim3(1, 256), 256, 0, stream>>>(t, outWt, out_b,
                                                      enc + (size_t)hf * 32768 * 32, 128, 512);
  }

  d1_part<<<256, 256, 0, stream>>>(enc, d1W, pz);
  d1_fin<<<64, 256, 0, stream>>>(pz, d1b, bn1g, bn1b, bn1m, bn1v, h1);
  d2_k<<<64, 128, 0, stream>>>(h1, d2W, d2b, bn2g, bn2b, bn2m, bn2v, h2);
  fin_k<<<1, 64, 0, stream>>>(h2, finW, finb, (float*)d_out);
}

// Round 5
// 3710.052 us; speedup vs baseline: 1.2539x; 1.1501x over previous
//
#include <hip/hip_runtime.h>

#define DEV __device__ __forceinline__

using bf16x8 = __attribute__((ext_vector_type(8))) __bf16;
using f32x4  = __attribute__((ext_vector_type(4))) float;
using u16x8  = __attribute__((ext_vector_type(8))) unsigned short;

DEV unsigned short f2bf(float f) {
  unsigned u = __builtin_bit_cast(unsigned, f);
  u += 0x7fffu + ((u >> 16) & 1u);
  return (unsigned short)(u >> 16);
}
DEV float bf2f(unsigned short h) {
  unsigned u = ((unsigned)h) << 16;
  return __builtin_bit_cast(float, u);
}
DEV f32x4 mfma16(u16x8 a, u16x8 b, f32x4 c) {
  return __builtin_amdgcn_mfma_f32_16x16x32_bf16(
      __builtin_bit_cast(bf16x8, a), __builtin_bit_cast(bf16x8, b), c, 0, 0, 0);
}
DEV f32x4 zero4() { f32x4 z = {0.f, 0.f, 0.f, 0.f}; return z; }

// async global->LDS, 16B per lane. lds dest = wave-uniform base + lane*16.
DEV void glds16(const unsigned short* g, unsigned short* l) {
  __builtin_amdgcn_global_load_lds(
      (const __attribute__((address_space(1))) unsigned int*)g,
      (__attribute__((address_space(3))) unsigned int*)l, 16, 0, 0);
}

// ---------------------------------------------------------------------------
// m97-style bf16 MFMA GEMM: C[M x N] = A[M x K] * Bt[N x K]^T + bias.
// 128x128 tile, BK=32, global_load_lds width-16 staging, UNPADDED LDS.
// ---------------------------------------------------------------------------
enum { EPI_BIAS = 0, EPI_RELU = 1, EPI_OUT = 2 };

template <int EPI>
__global__ __launch_bounds__(256) void gemm_k(
    const unsigned short* __restrict__ A, const unsigned short* __restrict__ Bt,
    const float* __restrict__ bias, unsigned short* __restrict__ C, int N, int K) {
  __shared__ unsigned short As[128 * 32];  // 8 KB, row-major, no pad
  __shared__ unsigned short Bs[128 * 32];
  const int tid = threadIdx.x;
  const int lane = tid & 63, wv = tid >> 6;
  const int q = lane >> 4, ln = lane & 15;
  const int wr = wv >> 1, wc = wv & 1;
  const int m0 = blockIdx.y << 7, n0 = blockIdx.x << 7;

  f32x4 acc[4][4];
#pragma unroll
  for (int i = 0; i < 4; ++i)
#pragma unroll
    for (int j = 0; j < 4; ++j) acc[i][j] = zero4();

  const int r0 = tid >> 2, c0 = (tid & 3) << 3;
  const unsigned short* Ap0 = A + (size_t)(m0 + r0) * K + c0;
  const unsigned short* Ap1 = A + (size_t)(m0 + r0 + 64) * K + c0;
  const unsigned short* Bp0 = Bt + (size_t)(n0 + r0) * K + c0;
  const unsigned short* Bp1 = Bt + (size_t)(n0 + r0 + 64) * K + c0;
  unsigned short* AsL0 = As + wv * 512;
  unsigned short* AsL1 = As + 2048 + wv * 512;
  unsigned short* BsL0 = Bs + wv * 512;
  unsigned short* BsL1 = Bs + 2048 + wv * 512;

  for (int kb = 0; kb < K; kb += 32) {
    __syncthreads();
    glds16(Ap0 + kb, AsL0);
    glds16(Ap1 + kb, AsL1);
    glds16(Bp0 + kb, BsL0);
    glds16(Bp1 + kb, BsL1);
    __syncthreads();
    u16x8 af[4];
#pragma unroll
    for (int mt = 0; mt < 4; ++mt)
      af[mt] = *(const u16x8*)(As + (wr * 64 + mt * 16 + ln) * 32 + q * 8);
#pragma unroll
    for (int nt = 0; nt < 4; ++nt) {
      u16x8 bf = *(const u16x8*)(Bs + (wc * 64 + nt * 16 + ln) * 32 + q * 8);
#pragma unroll
      for (int mt = 0; mt < 4; ++mt) acc[mt][nt] = mfma16(af[mt], bf, acc[mt][nt]);
    }
  }

#pragma unroll
  for (int mt = 0; mt < 4; ++mt) {
    const int rowb = m0 + wr * 64 + mt * 16 + q * 4;
#pragma unroll
    for (int nt = 0; nt < 4; ++nt) {
      const int col = n0 + wc * 64 + nt * 16 + ln;
      if (EPI == EPI_OUT && col >= 32) continue;
      const float bs = bias[col];
      const int ldc = (EPI == EPI_OUT) ? 32 : N;
#pragma unroll
      for (int r = 0; r < 4; ++r) {
        float v = acc[mt][nt][r] + bs;
        if (EPI == EPI_RELU) v = fmaxf(v, 0.f);
        C[(size_t)(rowb + r) * ldc + col] = f2bf(v);
      }
    }
  }
}

// ---------------------------------------------------------------------------
// V transpose: big V-cols [32768 tok x 1536 (+1024 off)] -> vt[(seq*8+h)*64+hd][512 key]
// grid (512 = seq*8+h, 8 key-tiles), block 256.
// ---------------------------------------------------------------------------
__global__ __launch_bounds__(256) void vt_k(const unsigned short* __restrict__ big,
                                            unsigned short* __restrict__ vt) {
  __shared__ unsigned short td[64 * 72];
  const int tid = threadIdx.x;
  const int sh = blockIdx.x;           // seq*8 + h
  const int seq = sh >> 3, h = sh & 7;
  const int kt = blockIdx.y;           // key tile of 64
  {
    const int key = tid >> 2, hdc = (tid & 3) << 4;
    const unsigned short* src =
        big + ((size_t)seq * 512 + kt * 64 + key) * 1536 + 1024 + h * 64 + hdc;
    *(u16x8*)(td + key * 72 + hdc) = *(const u16x8*)src;
    *(u16x8*)(td + key * 72 + hdc + 8) = *(const u16x8*)(src + 8);
  }
  __syncthreads();
  {
    const int hd = tid >> 2, kc = (tid & 3) << 4;
    u16x8 a, b;
#pragma unroll
    for (int j = 0; j < 8; ++j) a[j] = td[(kc + j) * 72 + hd];
#pragma unroll
    for (int j = 0; j < 8; ++j) b[j] = td[(kc + 8 + j) * 72 + hd];
    unsigned short* dst = vt + ((size_t)sh * 64 + hd) * 512 + kt * 64 + kc;
    *(u16x8*)dst = a;
    *(u16x8*)(dst + 8) = b;
  }
}

// ---------------------------------------------------------------------------
// Flash attention with alibi, NO max-subtraction (scores bounded; exp2 direct).
// qkv: [32768 tok x 1536] bf16 (q|k|v), vt: pre-transposed V [sh*64+hd][512].
// grid (seq*8, qt=4), block 256. Writes o [32768 x 512] bf16.
// ---------------------------------------------------------------------------
__global__ __launch_bounds__(256) void attn_k(const unsigned short* __restrict__ qkv,
                                              const unsigned short* __restrict__ vt,
                                              unsigned short* __restrict__ o) {
  __shared__ unsigned short Qs[128 * 72];
  __shared__ unsigned short Ks[64 * 72];
  __shared__ unsigned short Vts[64 * 72];  // [hd][key] (from vt, stride-72)
  __shared__ unsigned short Ps[128 * 72];
  const int tid = threadIdx.x;
  const int lane = tid & 63, w = tid >> 6, q = lane >> 4, ln = lane & 15;
  const int bh = blockIdx.x;
  const int seq = bh >> 3, h = bh & 7;
  const int qt = blockIdx.y;
  const size_t tokb = (size_t)seq * 512;
  const int qoff = h * 64, koff = 512 + h * 64;
  const float c1 = 0.125f * 1.44269504f;               // scale * log2e
  const float c2 = ((h < 4) ? 1.0f : 0.5f) * 1.44269504f;  // slope * log2e

#pragma unroll
  for (int p = 0; p < 4; ++p) {  // stage Q 128x64
    int c = p * 256 + tid;
    int row = c >> 3, cc = (c & 7) << 3;
    u16x8 v = *(const u16x8*)(qkv + (tokb + qt * 128 + row) * 1536 + qoff + cc);
    *(u16x8*)(Qs + row * 72 + cc) = v;
  }
  __syncthreads();
  u16x8 aq[2][2];
#pragma unroll
  for (int mt = 0; mt < 2; ++mt)
#pragma unroll
    for (int kc = 0; kc < 2; ++kc)
      aq[mt][kc] = *(const u16x8*)(Qs + (w * 32 + mt * 16 + ln) * 72 + kc * 32 + q * 8);

  float lacc[2][4];
  f32x4 o_acc[2][4];
#pragma unroll
  for (int mt = 0; mt < 2; ++mt)
#pragma unroll
    for (int r = 0; r < 4; ++r) lacc[mt][r] = 0.f;
#pragma unroll
  for (int mt = 0; mt < 2; ++mt)
#pragma unroll
    for (int ht = 0; ht < 4; ++ht) o_acc[mt][ht] = zero4();

  const int krow = tid >> 3, kcc = (tid & 7) << 3;
  const int vhd = tid >> 2, vc = (tid & 3) << 4;
  const unsigned short* vbase = vt + ((size_t)bh * 64 + vhd) * 512 + vc;

  for (int kt = 0; kt < 8; ++kt) {
    __syncthreads();
    {
      u16x8 v0 = *(const u16x8*)(qkv + (tokb + kt * 64 + krow) * 1536 + koff + kcc);
      u16x8 v1 = *(const u16x8*)(qkv + (tokb + kt * 64 + krow + 32) * 1536 + koff + kcc);
      *(u16x8*)(Ks + krow * 72 + kcc) = v0;
      *(u16x8*)(Ks + (krow + 32) * 72 + kcc) = v1;
      u16x8 w0 = *(const u16x8*)(vbase + kt * 64);
      u16x8 w1 = *(const u16x8*)(vbase + kt * 64 + 8);
      *(u16x8*)(Vts + vhd * 72 + vc) = w0;
      *(u16x8*)(Vts + vhd * 72 + vc + 8) = w1;
    }
    __syncthreads();

    f32x4 sacc[2][4];
#pragma unroll
    for (int mt = 0; mt < 2; ++mt)
#pragma unroll
      for (int nt = 0; nt < 4; ++nt) sacc[mt][nt] = zero4();
#pragma unroll
    for (int nt = 0; nt < 4; ++nt)
#pragma unroll
      for (int kc = 0; kc < 2; ++kc) {
        u16x8 bk = *(const u16x8*)(Ks + (nt * 16 + ln) * 72 + kc * 32 + q * 8);
#pragma unroll
        for (int mt = 0; mt < 2; ++mt) sacc[mt][nt] = mfma16(aq[mt][kc], bk, sacc[mt][nt]);
      }

    // P = exp2(S*c1 - c2*|dq-dk|); no max-subtract, no rescale.
    const float kbase = (float)(kt * 64 + ln);
#pragma unroll
    for (int mt = 0; mt < 2; ++mt) {
      const float qpb = (float)(qt * 128 + w * 32 + mt * 16 + q * 4);
#pragma unroll
      for (int nt = 0; nt < 4; ++nt) {
        const float kp = kbase + (float)(nt * 16);
#pragma unroll
        for (int r = 0; r < 4; ++r) {
          const float ad = fabsf(qpb + (float)r - kp);
          const float p = exp2f(fmaf(sacc[mt][nt][r], c1, -c2 * ad));
          const unsigned u = __builtin_bit_cast(unsigned, p);
          const unsigned short pb = (unsigned short)((u + 0x8000u) >> 16);
          Ps[(w * 32 + mt * 16 + q * 4 + r) * 72 + nt * 16 + ln] = pb;
          lacc[mt][r] += bf2f(pb);  // sum of the *stored* values -> div cancels bias
        }
      }
    }
    // P @ V  (Ps rows are wave-private; in-wave LDS ordering suffices)
#pragma unroll
    for (int kc = 0; kc < 2; ++kc) {
      u16x8 pa[2];
#pragma unroll
      for (int mt = 0; mt < 2; ++mt)
        pa[mt] = *(const u16x8*)(Ps + (w * 32 + mt * 16 + ln) * 72 + kc * 32 + q * 8);
#pragma unroll
      for (int ht = 0; ht < 4; ++ht) {
        u16x8 bv = *(const u16x8*)(Vts + (ht * 16 + ln) * 72 + kc * 32 + q * 8);
#pragma unroll
        for (int mt = 0; mt < 2; ++mt) o_acc[mt][ht] = mfma16(pa[mt], bv, o_acc[mt][ht]);
      }
    }
  }

  float rl[2][4];
#pragma unroll
  for (int mt = 0; mt < 2; ++mt)
#pragma unroll
    for (int r = 0; r < 4; ++r) {
      float l = lacc[mt][r];
#pragma unroll
      for (int msk = 1; msk < 16; msk <<= 1) l += __shfl_xor(l, msk, 64);
      rl[mt][r] = 1.0f / l;
    }

#pragma unroll
  for (int mt = 0; mt < 2; ++mt)
#pragma unroll
    for (int ht = 0; ht < 4; ++ht)
#pragma unroll
      for (int r = 0; r < 4; ++r) {
        const int row = qt * 128 + w * 32 + mt * 16 + q * 4 + r;
        const float val = o_acc[mt][ht][r] * rl[mt][r];
        o[(tokb + row) * 512 + h * 64 + ht * 16 + ln] = f2bf(val);
      }
}

// ---------------------------------------------------------------------------
// Fused residual + LayerNorm (in-place capable)
// ---------------------------------------------------------------------------
__global__ __launch_bounds__(256) void ln_k(const unsigned short* res,
                                            const unsigned short* __restrict__ y,
                                            const float* __restrict__ g,
                                            const float* __restrict__ b,
                                            unsigned short* out) {
  const int lane = threadIdx.x & 63, wv = threadIdx.x >> 6;
  const size_t row = (size_t)blockIdx.x * 4 + wv;
  const size_t base = row * 512 + lane * 8;
  u16x8 rv = *(const u16x8*)(res + base);
  u16x8 yv = *(const u16x8*)(y + base);
  float v[8];
  float s = 0.f, s2 = 0.f;
#pragma unroll
  for (int i = 0; i < 8; ++i) {
    v[i] = bf2f(rv[i]) + bf2f(yv[i]);
    s += v[i];
    s2 += v[i] * v[i];
  }
#pragma unroll
  for (int m = 1; m < 64; m <<= 1) {
    s += __shfl_xor(s, m, 64);
    s2 += __shfl_xor(s2, m, 64);
  }
  const float mean = s * (1.f / 512.f);
  const float var = s2 * (1.f / 512.f) - mean * mean;
  const float rstd = rsqrtf(var + 1e-5f);
  const int c = lane * 8;
  u16x8 ov;
#pragma unroll
  for (int i = 0; i < 8; ++i) ov[i] = f2bf((v[i] - mean) * rstd * g[c + i] + b[c + i]);
  *(u16x8*)(out + base) = ov;
}

// ---------------------------------------------------------------------------
// Weight transpose fp32 (Kin x Nin) -> bf16 (Nout x Kout), zero-padded.
// ---------------------------------------------------------------------------
__global__ __launch_bounds__(256) void transpose_w(const float* __restrict__ in,
                                                   unsigned short* __restrict__ out,
                                                   int Kin, int Nin, int Kout, int Nout) {
  __shared__ float tile[32][33];
  const int nb = blockIdx.x * 32, kb = blockIdx.y * 32;
  const int tx = threadIdx.x & 31, ty = threadIdx.x >> 5;
#pragma unroll
  for (int i = 0; i < 32; i += 8) {
    int k = kb + ty + i, n = nb + tx;
    tile[ty + i][tx] = (k < Kin && n < Nin) ? in[(size_t)k * Nin + n] : 0.f;
  }
  __syncthreads();
#pragma unroll
  for (int i = 0; i < 32; i += 8) {
    int n = nb + ty + i, k = kb + tx;
    if (n < Nout && k < Kout) out[(size_t)n * Kout + k] = f2bf(tile[tx][ty + i]);
  }
}

// x (64 x 20480) fp32 -> xpad (65536 tok x 32) bf16 (K padded 20->32)
__global__ __launch_bounds__(256) void xpad_k(const float* __restrict__ x,
                                              unsigned short* __restrict__ xp) {
  const int idx = blockIdx.x * 256 + threadIdx.x;  // 65536*32
  const int tok = idx >> 5, k = idx & 31;
  const int seq = tok >> 9, s = tok & 511;
  const int hf = seq >> 6, b = seq & 63;
  float v = 0.f;
  if (k < 20) v = x[(size_t)b * 20480 + hf * 10240 + s * 20 + k];
  xp[idx] = f2bf(v);
}

// ---------------------------------------------------------------------------
// Head d1: h(64 x 32768) @ d1_W(32768 x 256). 256 K-slices of 128; W read once.
// ---------------------------------------------------------------------------
__global__ __launch_bounds__(256) void d1_part(const unsigned short* __restrict__ enc,
                                               const float* __restrict__ W,
                                               float* __restrict__ pz) {
  __shared__ float ef[64 * 128];  // 32 KB
  const int tid = threadIdx.x;
  const int kb = blockIdx.x * 128;
  const int hf = kb >> 14;
  const int j0 = kb & 16383;
  {
    const int m = tid >> 2, c = (tid & 3) * 32;
    const unsigned short* src = enc + (size_t)hf * 1048576 + (size_t)m * 16384 + j0 + c;
#pragma unroll
    for (int i = 0; i < 4; ++i) {
      u16x8 v = *(const u16x8*)(src + i * 8);
#pragma unroll
      for (int jj = 0; jj < 8; ++jj) ef[m * 128 + c + i * 8 + jj] = bf2f(v[jj]);
    }
  }
  __syncthreads();
  const int n = tid;
  float acc[64];
#pragma unroll
  for (int m = 0; m < 64; ++m) acc[m] = 0.f;
  for (int kc = 0; kc < 128; kc += 4) {
    const float w0 = W[(size_t)(kb + kc) * 256 + n];
    const float w1 = W[(size_t)(kb + kc + 1) * 256 + n];
    const float w2 = W[(size_t)(kb + kc + 2) * 256 + n];
    const float w3 = W[(size_t)(kb + kc + 3) * 256 + n];
#pragma unroll
    for (int m = 0; m < 64; ++m) {
      const f32x4 e = *(const f32x4*)(ef + m * 128 + kc);
      acc[m] += e[0] * w0 + e[1] * w1 + e[2] * w2 + e[3] * w3;
    }
  }
#pragma unroll
  for (int m = 0; m < 64; ++m)
    pz[(size_t)(blockIdx.x * 64 + m) * 256 + n] = acc[m];
}

__global__ __launch_bounds__(256) void d1_fin(const float* __restrict__ pz,
                                              const float* __restrict__ d1b,
                                              const float* __restrict__ g,
                                              const float* __restrict__ b,
                                              const float* __restrict__ mm,
                                              const float* __restrict__ vv,
                                              float* __restrict__ h1) {
  const int m = blockIdx.x, n = threadIdx.x;
  float a = d1b[n];
  for (int sl = 0; sl < 256; ++sl) a += pz[(size_t)(sl * 64 + m) * 256 + n];
  a = fmaxf(a, 0.f);
  a = (a - mm[n]) * rsqrtf(vv[n] + 1e-5f) * g[n] + b[n];
  h1[m * 256 + n] = a;
}

__global__ __launch_bounds__(128) void d2_k(const float* __restrict__ h1,
                                            const float* __restrict__ W,
                                            const float* __restrict__ bb,
                                            const float* __restrict__ g,
                                            const float* __restrict__ b,
                                            const float* __restrict__ mm,
                                            const float* __restrict__ vv,
                                            float* __restrict__ h2) {
  __shared__ float hs[256];
  const int m = blockIdx.x, n = threadIdx.x;
  hs[n] = h1[m * 256 + n];
  hs[n + 128] = h1[m * 256 + n + 128];
  __syncthreads();
  float a = bb[n];
#pragma unroll 8
  for (int k = 0; k < 256; ++k) a += hs[k] * W[k * 128 + n];
  a = fmaxf(a, 0.f);
  a = (a - mm[n]) * rsqrtf(vv[n] + 1e-5f) * g[n] + b[n];
  h2[m * 128 + n] = a;
}

__global__ __launch_bounds__(64) void fin_k(const float* __restrict__ h2,
                                            const float* __restrict__ W,
                                            const float* __restrict__ fb,
                                            float* __restrict__ out) {
  const int m = threadIdx.x;
  float a = fb[0];
#pragma unroll 8
  for (int k = 0; k < 128; ++k) a += h2[m * 128 + k] * W[k];
  out[m] = a;
}

// ---------------------------------------------------------------------------
extern "C" void kernel_launch(void* const* d_in, const int* in_sizes, int n_in,
                              void* d_out, int out_size, void* d_ws, size_t ws_size,
                              hipStream_t stream) {
  const float* x      = (const float*)d_in[0];
  const float* in_W   = (const float*)d_in[1];
  const float* in_b   = (const float*)d_in[2];
  const float* qkv_W  = (const float*)d_in[3];
  const float* qkv_b  = (const float*)d_in[4];
  const float* ln1_g  = (const float*)d_in[5];
  const float* ln1_b  = (const float*)d_in[6];
  const float* ffn_W1 = (const float*)d_in[7];
  const float* ffn_b1 = (const float*)d_in[8];
  const float* ffn_W2 = (const float*)d_in[9];
  const float* ffn_b2 = (const float*)d_in[10];
  const float* ln2_g  = (const float*)d_in[11];
  const float* ln2_b  = (const float*)d_in[12];
  const float* out_W  = (const float*)d_in[13];
  const float* out_b  = (const float*)d_in[14];
  const float* d1W    = (const float*)d_in[15];
  const float* d1b    = (const float*)d_in[16];
  const float* bn1g   = (const float*)d_in[17];
  const float* bn1b   = (const float*)d_in[18];
  const float* bn1m   = (const float*)d_in[19];
  const float* bn1v   = (const float*)d_in[20];
  const float* d2W    = (const float*)d_in[21];
  const float* d2b    = (const float*)d_in[22];
  const float* bn2g   = (const float*)d_in[23];
  const float* bn2b   = (const float*)d_in[24];
  const float* bn2m   = (const float*)d_in[25];
  const float* bn2v   = (const float*)d_in[26];
  const float* finW   = (const float*)d_in[27];
  const float* finb   = (const float*)d_in[28];
  (void)in_sizes; (void)n_in; (void)out_size; (void)ws_size;

  char* ws = (char*)d_ws;
  size_t off = 0;
  auto alloc = [&](size_t bytes) {
    char* p = ws + off;
    off += (bytes + 255) & ~(size_t)255;
    return p;
  };
  unsigned short* t     = (unsigned short*)alloc(32768ull * 512 * 2);   //  33.5 MB
  unsigned short* big   = (unsigned short*)alloc(32768ull * 2048 * 2);  // 134 MB (qkv+vt / f1 / pz)
  unsigned short* ob    = (unsigned short*)alloc(32768ull * 512 * 2);   //  33.5 MB (o / y)
  unsigned short* xpad  = (unsigned short*)alloc(65536ull * 32 * 2);
  unsigned short* enc   = (unsigned short*)alloc(65536ull * 32 * 2);
  unsigned short* inWt  = (unsigned short*)alloc(512ull * 32 * 2);
  unsigned short* qkvWt = (unsigned short*)alloc(4ull * 1536 * 512 * 2);
  unsigned short* f1Wt  = (unsigned short*)alloc(4ull * 2048 * 512 * 2);
  unsigned short* f2Wt  = (unsigned short*)alloc(4ull * 512 * 2048 * 2);
  unsigned short* outWt = (unsigned short*)alloc(128ull * 512 * 2);
  float* h1 = (float*)alloc(64ull * 256 * 4);
  float* h2 = (float*)alloc(64ull * 128 * 4);
  float* pz = (float*)big;                               // big free by d1 time
  unsigned short* vtb = big + (size_t)32768 * 1536;      // upper 33.5 MB of big

  xpad_k<<<8192, 256, 0, stream>>>(x, xpad);
  transpose_w<<<dim3(16, 1), 256, 0, stream>>>(in_W, inWt, 20, 512, 32, 512);
  transpose_w<<<dim3(4, 16), 256, 0, stream>>>(out_W, outWt, 512, 32, 512, 128);
  for (int l = 0; l < 4; ++l) {
    transpose_w<<<dim3(48, 16), 256, 0, stream>>>(qkv_W + (size_t)l * 512 * 1536,
                                                  qkvWt + (size_t)l * 1536 * 512, 512, 1536, 512, 1536);
    transpose_w<<<dim3(64, 16), 256, 0, stream>>>(ffn_W1 + (size_t)l * 512 * 2048,
                                                  f1Wt + (size_t)l * 2048 * 512, 512, 2048, 512, 2048);
    transpose_w<<<dim3(16, 64), 256, 0, stream>>>(ffn_W2 + (size_t)l * 2048 * 512,
                                                  f2Wt + (size_t)l * 512 * 2048, 2048, 512, 2048, 512);
  }

  for (int hf = 0; hf < 2; ++hf) {
    gemm_k<EPI_BIAS><<<dim3(4, 256), 256, 0, stream>>>(xpad + (size_t)hf * 32768 * 32, inWt, in_b, t, 512, 32);
    for (int l = 0; l < 4; ++l) {
      gemm_k<EPI_BIAS><<<dim3(12, 256), 256, 0, stream>>>(t, qkvWt + (size_t)l * 1536 * 512,
                                                          qkv_b + l * 1536, big, 1536, 512);
      vt_k<<<dim3(512, 8), 256, 0, stream>>>(big, vtb);
      attn_k<<<dim3(512, 4), 256, 0, stream>>>(big, vtb, ob);
      ln_k<<<8192, 256, 0, stream>>>(t, ob, ln1_g + l * 512, ln1_b + l * 512, t);
      gemm_k<EPI_RELU><<<dim3(16, 256), 256, 0, stream>>>(t, f1Wt + (size_t)l * 2048 * 512,
                                                          ffn_b1 + l * 2048, big, 2048, 512);
      gemm_k<EPI_BIAS><<<dim3(4, 256), 256, 0, stream>>>(big, f2Wt + (size_t)l * 512 * 2048,
                                                         ffn_b2 + l * 512, ob, 512, 2048);
      ln_k<<<8192, 256, 0, stream>>>(t, ob, ln2_g + l * 512, ln2_b + l * 512, t);
    }
    gemm_k<EPI_OUT><<<dim3(1, 256), 256, 0, stream>>>(t, outWt, out_b,
                                                      enc + (size_t)hf * 32768 * 32, 128, 512);
  }

  d1_part<<<256, 256, 0, stream>>>(enc, d1W, pz);
  d1_fin<<<64, 256, 0, stream>>>(pz, d1b, bn1g, bn1b, bn1m, bn1v, h1);
  d2_k<<<64, 128, 0, stream>>>(h1, d2W, d2b, bn2g, bn2b, bn2m, bn2v, h2);
  fin_k<<<1, 64, 0, stream>>>(h2, finW, finb, (float*)d_out);
}

// Round 6
// 3522.738 us; speedup vs baseline: 1.3206x; 1.0532x over previous
//
#include <hip/hip_runtime.h>

#define DEV __device__ __forceinline__

using bf16x8 = __attribute__((ext_vector_type(8))) __bf16;
using f32x4  = __attribute__((ext_vector_type(4))) float;
using u16x8  = __attribute__((ext_vector_type(8))) unsigned short;

DEV unsigned short f2bf(float f) {
  unsigned u = __builtin_bit_cast(unsigned, f);
  u += 0x7fffu + ((u >> 16) & 1u);
  return (unsigned short)(u >> 16);
}
DEV float bf2f(unsigned short h) {
  unsigned u = ((unsigned)h) << 16;
  return __builtin_bit_cast(float, u);
}
DEV f32x4 mfma16(u16x8 a, u16x8 b, f32x4 c) {
  return __builtin_amdgcn_mfma_f32_16x16x32_bf16(
      __builtin_bit_cast(bf16x8, a), __builtin_bit_cast(bf16x8, b), c, 0, 0, 0);
}
DEV f32x4 zero4() { f32x4 z = {0.f, 0.f, 0.f, 0.f}; return z; }

// async global->LDS, 16B per lane. lds dest = wave-uniform base + lane*16.
DEV void glds16(const unsigned short* g, unsigned short* l) {
  __builtin_amdgcn_global_load_lds(
      (const __attribute__((address_space(1))) unsigned int*)g,
      (__attribute__((address_space(3))) unsigned int*)l, 16, 0, 0);
}

// ---------------------------------------------------------------------------
// m97-style bf16 MFMA GEMM: C[M x N] = A[M x K] * Bt[N x K]^T + bias.
// 128x128 tile, BK=32, global_load_lds width-16 staging, UNPADDED LDS.
// XCD-banded swizzle: linear%8 = XCD (heuristic); each XCD owns a contiguous
// M-band (Mt/8 strips = 4 MB -> fits its private L2), N sweeps fastest.
// Kills the 2x cross-XCD A-strip re-fetch (R5: FETCH 267 MB vs 136 unique).
// ---------------------------------------------------------------------------
enum { EPI_BIAS = 0, EPI_RELU = 1, EPI_OUT = 2 };

template <int EPI>
__global__ __launch_bounds__(256) void gemm_k(
    const unsigned short* __restrict__ A, const unsigned short* __restrict__ Bt,
    const float* __restrict__ bias, unsigned short* __restrict__ C, int N, int K) {
  __shared__ unsigned short As[128 * 32];  // 8 KB, row-major, no pad
  __shared__ unsigned short Bs[128 * 32];
  const int tid = threadIdx.x;
  const int lane = tid & 63, wv = tid >> 6;
  const int q = lane >> 4, ln = lane & 15;
  const int wr = wv >> 1, wc = wv & 1;

  // XCD-banded block swizzle (requires Mt%8==0; all our grids have Mt=256)
  const int Nt = gridDim.x, Mt = gridDim.y;
  const int lin = blockIdx.x + Nt * blockIdx.y;  // dispatch order: x fastest
  const int xcd = lin & 7;
  const int j = lin >> 3;
  const int mi = xcd * (Mt >> 3) + j / Nt;
  const int ni = j % Nt;
  const int m0 = mi << 7, n0 = ni << 7;

  f32x4 acc[4][4];
#pragma unroll
  for (int i = 0; i < 4; ++i)
#pragma unroll
    for (int jj = 0; jj < 4; ++jj) acc[i][jj] = zero4();

  const int r0 = tid >> 2, c0 = (tid & 3) << 3;
  const unsigned short* Ap0 = A + (size_t)(m0 + r0) * K + c0;
  const unsigned short* Ap1 = A + (size_t)(m0 + r0 + 64) * K + c0;
  const unsigned short* Bp0 = Bt + (size_t)(n0 + r0) * K + c0;
  const unsigned short* Bp1 = Bt + (size_t)(n0 + r0 + 64) * K + c0;
  unsigned short* AsL0 = As + wv * 512;
  unsigned short* AsL1 = As + 2048 + wv * 512;
  unsigned short* BsL0 = Bs + wv * 512;
  unsigned short* BsL1 = Bs + 2048 + wv * 512;

  for (int kb = 0; kb < K; kb += 32) {
    __syncthreads();
    glds16(Ap0 + kb, AsL0);
    glds16(Ap1 + kb, AsL1);
    glds16(Bp0 + kb, BsL0);
    glds16(Bp1 + kb, BsL1);
    __syncthreads();
    u16x8 af[4];
#pragma unroll
    for (int mt = 0; mt < 4; ++mt)
      af[mt] = *(const u16x8*)(As + (wr * 64 + mt * 16 + ln) * 32 + q * 8);
#pragma unroll
    for (int nt = 0; nt < 4; ++nt) {
      u16x8 bf = *(const u16x8*)(Bs + (wc * 64 + nt * 16 + ln) * 32 + q * 8);
#pragma unroll
      for (int mt = 0; mt < 4; ++mt) acc[mt][nt] = mfma16(af[mt], bf, acc[mt][nt]);
    }
  }

#pragma unroll
  for (int mt = 0; mt < 4; ++mt) {
    const int rowb = m0 + wr * 64 + mt * 16 + q * 4;
#pragma unroll
    for (int nt = 0; nt < 4; ++nt) {
      const int col = n0 + wc * 64 + nt * 16 + ln;
      if (EPI == EPI_OUT && col >= 32) continue;
      const float bs = bias[col];
      const int ldc = (EPI == EPI_OUT) ? 32 : N;
#pragma unroll
      for (int r = 0; r < 4; ++r) {
        float v = acc[mt][nt][r] + bs;
        if (EPI == EPI_RELU) v = fmaxf(v, 0.f);
        C[(size_t)(rowb + r) * ldc + col] = f2bf(v);
      }
    }
  }
}

// ---------------------------------------------------------------------------
// V transpose: big V-cols [32768 tok x 1536 (+1024 off)] -> vt[(seq*8+h)*64+hd][512 key]
// grid (512 = seq*8+h, 8 key-tiles), block 256.
// ---------------------------------------------------------------------------
__global__ __launch_bounds__(256) void vt_k(const unsigned short* __restrict__ big,
                                            unsigned short* __restrict__ vt) {
  __shared__ unsigned short td[64 * 72];
  const int tid = threadIdx.x;
  const int sh = blockIdx.x;           // seq*8 + h
  const int seq = sh >> 3, h = sh & 7;
  const int kt = blockIdx.y;           // key tile of 64
  {
    const int key = tid >> 2, hdc = (tid & 3) << 4;
    const unsigned short* src =
        big + ((size_t)seq * 512 + kt * 64 + key) * 1536 + 1024 + h * 64 + hdc;
    *(u16x8*)(td + key * 72 + hdc) = *(const u16x8*)src;
    *(u16x8*)(td + key * 72 + hdc + 8) = *(const u16x8*)(src + 8);
  }
  __syncthreads();
  {
    const int hd = tid >> 2, kc = (tid & 3) << 4;
    u16x8 a, b;
#pragma unroll
    for (int j = 0; j < 8; ++j) a[j] = td[(kc + j) * 72 + hd];
#pragma unroll
    for (int j = 0; j < 8; ++j) b[j] = td[(kc + 8 + j) * 72 + hd];
    unsigned short* dst = vt + ((size_t)sh * 64 + hd) * 512 + kt * 64 + kc;
    *(u16x8*)dst = a;
    *(u16x8*)(dst + 8) = b;
  }
}

// ---------------------------------------------------------------------------
// Flash attention with alibi, NO max-subtraction (scores bounded; exp2 direct).
// qkv: [32768 tok x 1536] bf16 (q|k|v), vt: pre-transposed V [sh*64+hd][512].
// grid (seq*8, qt=4), block 256. Writes o [32768 x 512] bf16.
// ---------------------------------------------------------------------------
__global__ __launch_bounds__(256) void attn_k(const unsigned short* __restrict__ qkv,
                                              const unsigned short* __restrict__ vt,
                                              unsigned short* __restrict__ o) {
  __shared__ unsigned short Qs[128 * 72];
  __shared__ unsigned short Ks[64 * 72];
  __shared__ unsigned short Vts[64 * 72];  // [hd][key] (from vt, stride-72)
  __shared__ unsigned short Ps[128 * 72];
  const int tid = threadIdx.x;
  const int lane = tid & 63, w = tid >> 6, q = lane >> 4, ln = lane & 15;
  const int bh = blockIdx.x;
  const int seq = bh >> 3, h = bh & 7;
  const int qt = blockIdx.y;
  const size_t tokb = (size_t)seq * 512;
  const int qoff = h * 64, koff = 512 + h * 64;
  const float c1 = 0.125f * 1.44269504f;               // scale * log2e
  const float c2 = ((h < 4) ? 1.0f : 0.5f) * 1.44269504f;  // slope * log2e

#pragma unroll
  for (int p = 0; p < 4; ++p) {  // stage Q 128x64
    int c = p * 256 + tid;
    int row = c >> 3, cc = (c & 7) << 3;
    u16x8 v = *(const u16x8*)(qkv + (tokb + qt * 128 + row) * 1536 + qoff + cc);
    *(u16x8*)(Qs + row * 72 + cc) = v;
  }
  __syncthreads();
  u16x8 aq[2][2];
#pragma unroll
  for (int mt = 0; mt < 2; ++mt)
#pragma unroll
    for (int kc = 0; kc < 2; ++kc)
      aq[mt][kc] = *(const u16x8*)(Qs + (w * 32 + mt * 16 + ln) * 72 + kc * 32 + q * 8);

  float lacc[2][4];
  f32x4 o_acc[2][4];
#pragma unroll
  for (int mt = 0; mt < 2; ++mt)
#pragma unroll
    for (int r = 0; r < 4; ++r) lacc[mt][r] = 0.f;
#pragma unroll
  for (int mt = 0; mt < 2; ++mt)
#pragma unroll
    for (int ht = 0; ht < 4; ++ht) o_acc[mt][ht] = zero4();

  const int krow = tid >> 3, kcc = (tid & 7) << 3;
  const int vhd = tid >> 2, vc = (tid & 3) << 4;
  const unsigned short* vbase = vt + ((size_t)bh * 64 + vhd) * 512 + vc;

  for (int kt = 0; kt < 8; ++kt) {
    __syncthreads();
    {
      u16x8 v0 = *(const u16x8*)(qkv + (tokb + kt * 64 + krow) * 1536 + koff + kcc);
      u16x8 v1 = *(const u16x8*)(qkv + (tokb + kt * 64 + krow + 32) * 1536 + koff + kcc);
      *(u16x8*)(Ks + krow * 72 + kcc) = v0;
      *(u16x8*)(Ks + (krow + 32) * 72 + kcc) = v1;
      u16x8 w0 = *(const u16x8*)(vbase + kt * 64);
      u16x8 w1 = *(const u16x8*)(vbase + kt * 64 + 8);
      *(u16x8*)(Vts + vhd * 72 + vc) = w0;
      *(u16x8*)(Vts + vhd * 72 + vc + 8) = w1;
    }
    __syncthreads();

    f32x4 sacc[2][4];
#pragma unroll
    for (int mt = 0; mt < 2; ++mt)
#pragma unroll
      for (int nt = 0; nt < 4; ++nt) sacc[mt][nt] = zero4();
#pragma unroll
    for (int nt = 0; nt < 4; ++nt)
#pragma unroll
      for (int kc = 0; kc < 2; ++kc) {
        u16x8 bk = *(const u16x8*)(Ks + (nt * 16 + ln) * 72 + kc * 32 + q * 8);
#pragma unroll
        for (int mt = 0; mt < 2; ++mt) sacc[mt][nt] = mfma16(aq[mt][kc], bk, sacc[mt][nt]);
      }

    // P = exp2(S*c1 - c2*|dq-dk|); no max-subtract, no rescale.
    const float kbase = (float)(kt * 64 + ln);
#pragma unroll
    for (int mt = 0; mt < 2; ++mt) {
      const float qpb = (float)(qt * 128 + w * 32 + mt * 16 + q * 4);
#pragma unroll
      for (int nt = 0; nt < 4; ++nt) {
        const float kp = kbase + (float)(nt * 16);
#pragma unroll
        for (int r = 0; r < 4; ++r) {
          const float ad = fabsf(qpb + (float)r - kp);
          const float p = exp2f(fmaf(sacc[mt][nt][r], c1, -c2 * ad));
          const unsigned u = __builtin_bit_cast(unsigned, p);
          const unsigned short pb = (unsigned short)((u + 0x8000u) >> 16);
          Ps[(w * 32 + mt * 16 + q * 4 + r) * 72 + nt * 16 + ln] = pb;
          lacc[mt][r] += bf2f(pb);  // sum of the *stored* values -> div cancels bias
        }
      }
    }
    // P @ V  (Ps rows are wave-private; in-wave LDS ordering suffices)
#pragma unroll
    for (int kc = 0; kc < 2; ++kc) {
      u16x8 pa[2];
#pragma unroll
      for (int mt = 0; mt < 2; ++mt)
        pa[mt] = *(const u16x8*)(Ps + (w * 32 + mt * 16 + ln) * 72 + kc * 32 + q * 8);
#pragma unroll
      for (int ht = 0; ht < 4; ++ht) {
        u16x8 bv = *(const u16x8*)(Vts + (ht * 16 + ln) * 72 + kc * 32 + q * 8);
#pragma unroll
        for (int mt = 0; mt < 2; ++mt) o_acc[mt][ht] = mfma16(pa[mt], bv, o_acc[mt][ht]);
      }
    }
  }

  float rl[2][4];
#pragma unroll
  for (int mt = 0; mt < 2; ++mt)
#pragma unroll
    for (int r = 0; r < 4; ++r) {
      float l = lacc[mt][r];
#pragma unroll
      for (int msk = 1; msk < 16; msk <<= 1) l += __shfl_xor(l, msk, 64);
      rl[mt][r] = 1.0f / l;
    }

#pragma unroll
  for (int mt = 0; mt < 2; ++mt)
#pragma unroll
    for (int ht = 0; ht < 4; ++ht)
#pragma unroll
      for (int r = 0; r < 4; ++r) {
        const int row = qt * 128 + w * 32 + mt * 16 + q * 4 + r;
        const float val = o_acc[mt][ht][r] * rl[mt][r];
        o[(tokb + row) * 512 + h * 64 + ht * 16 + ln] = f2bf(val);
      }
}

// ---------------------------------------------------------------------------
// Fused residual + LayerNorm (in-place capable)
// ---------------------------------------------------------------------------
__global__ __launch_bounds__(256) void ln_k(const unsigned short* res,
                                            const unsigned short* __restrict__ y,
                                            const float* __restrict__ g,
                                            const float* __restrict__ b,
                                            unsigned short* out) {
  const int lane = threadIdx.x & 63, wv = threadIdx.x >> 6;
  const size_t row = (size_t)blockIdx.x * 4 + wv;
  const size_t base = row * 512 + lane * 8;
  u16x8 rv = *(const u16x8*)(res + base);
  u16x8 yv = *(const u16x8*)(y + base);
  float v[8];
  float s = 0.f, s2 = 0.f;
#pragma unroll
  for (int i = 0; i < 8; ++i) {
    v[i] = bf2f(rv[i]) + bf2f(yv[i]);
    s += v[i];
    s2 += v[i] * v[i];
  }
#pragma unroll
  for (int m = 1; m < 64; m <<= 1) {
    s += __shfl_xor(s, m, 64);
    s2 += __shfl_xor(s2, m, 64);
  }
  const float mean = s * (1.f / 512.f);
  const float var = s2 * (1.f / 512.f) - mean * mean;
  const float rstd = rsqrtf(var + 1e-5f);
  const int c = lane * 8;
  u16x8 ov;
#pragma unroll
  for (int i = 0; i < 8; ++i) ov[i] = f2bf((v[i] - mean) * rstd * g[c + i] + b[c + i]);
  *(u16x8*)(out + base) = ov;
}

// ---------------------------------------------------------------------------
// Weight transpose fp32 (Kin x Nin) -> bf16 (Nout x Kout), zero-padded.
// ---------------------------------------------------------------------------
__global__ __launch_bounds__(256) void transpose_w(const float* __restrict__ in,
                                                   unsigned short* __restrict__ out,
                                                   int Kin, int Nin, int Kout, int Nout) {
  __shared__ float tile[32][33];
  const int nb = blockIdx.x * 32, kb = blockIdx.y * 32;
  const int tx = threadIdx.x & 31, ty = threadIdx.x >> 5;
#pragma unroll
  for (int i = 0; i < 32; i += 8) {
    int k = kb + ty + i, n = nb + tx;
    tile[ty + i][tx] = (k < Kin && n < Nin) ? in[(size_t)k * Nin + n] : 0.f;
  }
  __syncthreads();
#pragma unroll
  for (int i = 0; i < 32; i += 8) {
    int n = nb + ty + i, k = kb + tx;
    if (n < Nout && k < Kout) out[(size_t)n * Kout + k] = f2bf(tile[tx][ty + i]);
  }
}

// x (64 x 20480) fp32 -> xpad (65536 tok x 32) bf16 (K padded 20->32)
__global__ __launch_bounds__(256) void xpad_k(const float* __restrict__ x,
                                              unsigned short* __restrict__ xp) {
  const int idx = blockIdx.x * 256 + threadIdx.x;  // 65536*32
  const int tok = idx >> 5, k = idx & 31;
  const int seq = tok >> 9, s = tok & 511;
  const int hf = seq >> 6, b = seq & 63;
  float v = 0.f;
  if (k < 20) v = x[(size_t)b * 20480 + hf * 10240 + s * 20 + k];
  xp[idx] = f2bf(v);
}

// ---------------------------------------------------------------------------
// Head d1: h(64 x 32768) @ d1_W(32768 x 256). 256 K-slices of 128; W read once.
// ---------------------------------------------------------------------------
__global__ __launch_bounds__(256) void d1_part(const unsigned short* __restrict__ enc,
                                               const float* __restrict__ W,
                                               float* __restrict__ pz) {
  __shared__ float ef[64 * 128];  // 32 KB
  const int tid = threadIdx.x;
  const int kb = blockIdx.x * 128;
  const int hf = kb >> 14;
  const int j0 = kb & 16383;
  {
    const int m = tid >> 2, c = (tid & 3) * 32;
    const unsigned short* src = enc + (size_t)hf * 1048576 + (size_t)m * 16384 + j0 + c;
#pragma unroll
    for (int i = 0; i < 4; ++i) {
      u16x8 v = *(const u16x8*)(src + i * 8);
#pragma unroll
      for (int jj = 0; jj < 8; ++jj) ef[m * 128 + c + i * 8 + jj] = bf2f(v[jj]);
    }
  }
  __syncthreads();
  const int n = tid;
  float acc[64];
#pragma unroll
  for (int m = 0; m < 64; ++m) acc[m] = 0.f;
  for (int kc = 0; kc < 128; kc += 4) {
    const float w0 = W[(size_t)(kb + kc) * 256 + n];
    const float w1 = W[(size_t)(kb + kc + 1) * 256 + n];
    const float w2 = W[(size_t)(kb + kc + 2) * 256 + n];
    const float w3 = W[(size_t)(kb + kc + 3) * 256 + n];
#pragma unroll
    for (int m = 0; m < 64; ++m) {
      const f32x4 e = *(const f32x4*)(ef + m * 128 + kc);
      acc[m] += e[0] * w0 + e[1] * w1 + e[2] * w2 + e[3] * w3;
    }
  }
#pragma unroll
  for (int m = 0; m < 64; ++m)
    pz[(size_t)(blockIdx.x * 64 + m) * 256 + n] = acc[m];
}

__global__ __launch_bounds__(256) void d1_fin(const float* __restrict__ pz,
                                              const float* __restrict__ d1b,
                                              const float* __restrict__ g,
                                              const float* __restrict__ b,
                                              const float* __restrict__ mm,
                                              const float* __restrict__ vv,
                                              float* __restrict__ h1) {
  const int m = blockIdx.x, n = threadIdx.x;
  float a = d1b[n];
  for (int sl = 0; sl < 256; ++sl) a += pz[(size_t)(sl * 64 + m) * 256 + n];
  a = fmaxf(a, 0.f);
  a = (a - mm[n]) * rsqrtf(vv[n] + 1e-5f) * g[n] + b[n];
  h1[m * 256 + n] = a;
}

__global__ __launch_bounds__(128) void d2_k(const float* __restrict__ h1,
                                            const float* __restrict__ W,
                                            const float* __restrict__ bb,
                                            const float* __restrict__ g,
                                            const float* __restrict__ b,
                                            const float* __restrict__ mm,
                                            const float* __restrict__ vv,
                                            float* __restrict__ h2) {
  __shared__ float hs[256];
  const int m = blockIdx.x, n = threadIdx.x;
  hs[n] = h1[m * 256 + n];
  hs[n + 128] = h1[m * 256 + n + 128];
  __syncthreads();
  float a = bb[n];
#pragma unroll 8
  for (int k = 0; k < 256; ++k) a += hs[k] * W[k * 128 + n];
  a = fmaxf(a, 0.f);
  a = (a - mm[n]) * rsqrtf(vv[n] + 1e-5f) * g[n] + b[n];
  h2[m * 128 + n] = a;
}

__global__ __launch_bounds__(64) void fin_k(const float* __restrict__ h2,
                                            const float* __restrict__ W,
                                            const float* __restrict__ fb,
                                            float* __restrict__ out) {
  const int m = threadIdx.x;
  float a = fb[0];
#pragma unroll 8
  for (int k = 0; k < 128; ++k) a += h2[m * 128 + k] * W[k];
  out[m] = a;
}

// ---------------------------------------------------------------------------
extern "C" void kernel_launch(void* const* d_in, const int* in_sizes, int n_in,
                              void* d_out, int out_size, void* d_ws, size_t ws_size,
                              hipStream_t stream) {
  const float* x      = (const float*)d_in[0];
  const float* in_W   = (const float*)d_in[1];
  const float* in_b   = (const float*)d_in[2];
  const float* qkv_W  = (const float*)d_in[3];
  const float* qkv_b  = (const float*)d_in[4];
  const float* ln1_g  = (const float*)d_in[5];
  const float* ln1_b  = (const float*)d_in[6];
  const float* ffn_W1 = (const float*)d_in[7];
  const float* ffn_b1 = (const float*)d_in[8];
  const float* ffn_W2 = (const float*)d_in[9];
  const float* ffn_b2 = (const float*)d_in[10];
  const float* ln2_g  = (const float*)d_in[11];
  const float* ln2_b  = (const float*)d_in[12];
  const float* out_W  = (const float*)d_in[13];
  const float* out_b  = (const float*)d_in[14];
  const float* d1W    = (const float*)d_in[15];
  const float* d1b    = (const float*)d_in[16];
  const float* bn1g   = (const float*)d_in[17];
  const float* bn1b   = (const float*)d_in[18];
  const float* bn1m   = (const float*)d_in[19];
  const float* bn1v   = (const float*)d_in[20];
  const float* d2W    = (const float*)d_in[21];
  const float* d2b    = (const float*)d_in[22];
  const float* bn2g   = (const float*)d_in[23];
  const float* bn2b   = (const float*)d_in[24];
  const float* bn2m   = (const float*)d_in[25];
  const float* bn2v   = (const float*)d_in[26];
  const float* finW   = (const float*)d_in[27];
  const float* finb   = (const float*)d_in[28];
  (void)in_sizes; (void)n_in; (void)out_size; (void)ws_size;

  char* ws = (char*)d_ws;
  size_t off = 0;
  auto alloc = [&](size_t bytes) {
    char* p = ws + off;
    off += (bytes + 255) & ~(size_t)255;
    return p;
  };
  unsigned short* t     = (unsigned short*)alloc(32768ull * 512 * 2);   //  33.5 MB
  unsigned short* big   = (unsigned short*)alloc(32768ull * 2048 * 2);  // 134 MB (qkv+vt / f1 / pz)
  unsigned short* ob    = (unsigned short*)alloc(32768ull * 512 * 2);   //  33.5 MB (o / y)
  unsigned short* xpad  = (unsigned short*)alloc(65536ull * 32 * 2);
  unsigned short* enc   = (unsigned short*)alloc(65536ull * 32 * 2);
  unsigned short* inWt  = (unsigned short*)alloc(512ull * 32 * 2);
  unsigned short* qkvWt = (unsigned short*)alloc(4ull * 1536 * 512 * 2);
  unsigned short* f1Wt  = (unsigned short*)alloc(4ull * 2048 * 512 * 2);
  unsigned short* f2Wt  = (unsigned short*)alloc(4ull * 512 * 2048 * 2);
  unsigned short* outWt = (unsigned short*)alloc(128ull * 512 * 2);
  float* h1 = (float*)alloc(64ull * 256 * 4);
  float* h2 = (float*)alloc(64ull * 128 * 4);
  float* pz = (float*)big;                               // big free by d1 time
  unsigned short* vtb = big + (size_t)32768 * 1536;      // upper 33.5 MB of big

  xpad_k<<<8192, 256, 0, stream>>>(x, xpad);
  transpose_w<<<dim3(16, 1), 256, 0, stream>>>(in_W, inWt, 20, 512, 32, 512);
  transpose_w<<<dim3(4, 16), 256, 0, stream>>>(out_W, outWt, 512, 32, 512, 128);
  for (int l = 0; l < 4; ++l) {
    transpose_w<<<dim3(48, 16), 256, 0, stream>>>(qkv_W + (size_t)l * 512 * 1536,
                                                  qkvWt + (size_t)l * 1536 * 512, 512, 1536, 512, 1536);
    transpose_w<<<dim3(64, 16), 256, 0, stream>>>(ffn_W1 + (size_t)l * 512 * 2048,
                                                  f1Wt + (size_t)l * 2048 * 512, 512, 2048, 512, 2048);
    transpose_w<<<dim3(16, 64), 256, 0, stream>>>(ffn_W2 + (size_t)l * 2048 * 512,
                                                  f2Wt + (size_t)l * 512 * 2048, 2048, 512, 2048, 512);
  }

  for (int hf = 0; hf < 2; ++hf) {
    gemm_k<EPI_BIAS><<<dim3(4, 256), 256, 0, stream>>>(xpad + (size_t)hf * 32768 * 32, inWt, in_b, t, 512, 32);
    for (int l = 0; l < 4; ++l) {
      gemm_k<EPI_BIAS><<<dim3(12, 256), 256, 0, stream>>>(t, qkvWt + (size_t)l * 1536 * 512,
                                                          qkv_b + l * 1536, big, 1536, 512);
      vt_k<<<dim3(512, 8), 256, 0, stream>>>(big, vtb);
      attn_k<<<dim3(512, 4), 256, 0, stream>>>(big, vtb, ob);
      ln_k<<<8192, 256, 0, stream>>>(t, ob, ln1_g + l * 512, ln1_b + l * 512, t);
      gemm_k<EPI_RELU><<<dim3(16, 256), 256, 0, stream>>>(t, f1Wt + (size_t)l * 2048 * 512,
                                                          ffn_b1 + l * 2048, big, 2048, 512);
      gemm_k<EPI_BIAS><<<dim3(4, 256), 256, 0, stream>>>(big, f2Wt + (size_t)l * 512 * 2048,
                                                         ffn_b2 + l * 512, ob, 512, 2048);
      ln_k<<<8192, 256, 0, stream>>>(t, ob, ln2_g + l * 512, ln2_b + l * 512, t);
    }
    gemm_k<EPI_OUT><<<dim3(1, 256), 256, 0, stream>>>(t, outWt, out_b,
                                                      enc + (size_t)hf * 32768 * 32, 128, 512);
  }

  d1_part<<<256, 256, 0, stream>>>(enc, d1W, pz);
  d1_fin<<<64, 256, 0, stream>>>(pz, d1b, bn1g, bn1b, bn1m, bn1v, h1);
  d2_k<<<64, 128, 0, stream>>>(h1, d2W, d2b, bn2g, bn2b, bn2m, bn2v, h2);
  fin_k<<<1, 64, 0, stream>>>(h2, finW, finb, (float*)d_out);
}

// Round 7
// 3497.086 us; speedup vs baseline: 1.3303x; 1.0073x over previous
//
#include <hip/hip_runtime.h>

#define DEV __device__ __forceinline__

using bf16x8 = __attribute__((ext_vector_type(8))) __bf16;
using f32x4  = __attribute__((ext_vector_type(4))) float;
using u16x8  = __attribute__((ext_vector_type(8))) unsigned short;

DEV unsigned short f2bf(float f) {
  unsigned u = __builtin_bit_cast(unsigned, f);
  u += 0x7fffu + ((u >> 16) & 1u);
  return (unsigned short)(u >> 16);
}
DEV float bf2f(unsigned short h) {
  unsigned u = ((unsigned)h) << 16;
  return __builtin_bit_cast(float, u);
}
DEV f32x4 mfma16(u16x8 a, u16x8 b, f32x4 c) {
  return __builtin_amdgcn_mfma_f32_16x16x32_bf16(
      __builtin_bit_cast(bf16x8, a), __builtin_bit_cast(bf16x8, b), c, 0, 0, 0);
}
DEV f32x4 zero4() { f32x4 z = {0.f, 0.f, 0.f, 0.f}; return z; }

// async global->LDS, 16B per lane. lds dest = wave-uniform base + lane*16;
// global src is per-lane.
DEV void glds16(const unsigned short* g, unsigned short* l) {
  __builtin_amdgcn_global_load_lds(
      (const __attribute__((address_space(1))) unsigned int*)g,
      (__attribute__((address_space(3))) unsigned int*)l, 16, 0, 0);
}

// ---------------------------------------------------------------------------
// bf16 MFMA GEMM: C[M x N] = A[M x K] * Bt[N x K]^T + bias. 128x128 tile.
// BK=64 (halves barrier count vs BK=32) + XOR-swizzled LDS chunk layout:
//   16-B chunk of (row r, col-chunk c) lives at slot r*8 + (c ^ (r&7)).
//   -> staging glds16 stays coalesced (in-row source permutation),
//   -> ds_read_b128 fragment reads are 2-way-per-bank (free, m136),
//      vs 8.4M conflict cycles/dispatch with the old row-major BK=32 tile.
// XCD-banded block swizzle (linear%8 = XCD): each XCD owns a contiguous
// M-band -> A-strips fetched into exactly one XCD's L2 (R6: FETCH 267->82 MB).
// Requires K % 64 == 0 (in-proj inputs padded to K=64).
// ---------------------------------------------------------------------------
enum { EPI_BIAS = 0, EPI_RELU = 1, EPI_OUT = 2 };

template <int EPI>
__global__ __launch_bounds__(256) void gemm_k(
    const unsigned short* __restrict__ A, const unsigned short* __restrict__ Bt,
    const float* __restrict__ bias, unsigned short* __restrict__ C, int N, int K) {
  __shared__ unsigned short As[128 * 64];  // 16 KB, swizzled chunks
  __shared__ unsigned short Bs[128 * 64];
  const int tid = threadIdx.x;
  const int lane = tid & 63, wv = tid >> 6;
  const int q = lane >> 4, ln = lane & 15;
  const int wr = wv >> 1, wc = wv & 1;

  const int Nt = gridDim.x, Mt = gridDim.y;
  const int lin = blockIdx.x + Nt * blockIdx.y;
  const int xcd = lin & 7;
  const int j = lin >> 3;
  const int mi = xcd * (Mt >> 3) + j / Nt;
  const int ni = j % Nt;
  const int m0 = mi << 7, n0 = ni << 7;

  f32x4 acc[4][4];
#pragma unroll
  for (int i = 0; i < 4; ++i)
#pragma unroll
    for (int jj = 0; jj < 4; ++jj) acc[i][jj] = zero4();

  // staging: 16 issues/tile; wave wv does issues wv*4+t (rows wv*32+t*8+ra)
  const int ra = lane >> 3;              // row within 8-row group
  const int ca = ((lane & 7) ^ ra) << 3; // swizzled source col-chunk (shorts)
  const unsigned short* Ap = A + (size_t)(m0 + wv * 32 + ra) * K + ca;
  const unsigned short* Bp = Bt + (size_t)(n0 + wv * 32 + ra) * K + ca;
  unsigned short* AsW = As + wv * 2048;  // 4 issues x 512 shorts
  unsigned short* BsW = Bs + wv * 2048;
  const int ln7 = ln & 7;

  for (int kb = 0; kb < K; kb += 64) {
    __syncthreads();  // WAR: prior ds_reads done before overwrite
#pragma unroll
    for (int t = 0; t < 4; ++t) {
      glds16(Ap + (size_t)(t * 8) * K + kb, AsW + t * 512);
      glds16(Bp + (size_t)(t * 8) * K + kb, BsW + t * 512);
    }
    __syncthreads();  // barrier drains vmcnt -> tiles visible
#pragma unroll
    for (int kk = 0; kk < 2; ++kk) {
      const int c = kk * 4 + q;
      const int lo = ln * 64 + ((c ^ ln7) << 3);  // lane offset (shorts)
      u16x8 af[4];
#pragma unroll
      for (int mt = 0; mt < 4; ++mt)
        af[mt] = *(const u16x8*)(As + (wr * 64 + mt * 16) * 64 + lo);
#pragma unroll
      for (int nt = 0; nt < 4; ++nt) {
        u16x8 bf = *(const u16x8*)(Bs + (wc * 64 + nt * 16) * 64 + lo);
#pragma unroll
        for (int mt = 0; mt < 4; ++mt) acc[mt][nt] = mfma16(af[mt], bf, acc[mt][nt]);
      }
    }
  }

#pragma unroll
  for (int mt = 0; mt < 4; ++mt) {
    const int rowb = m0 + wr * 64 + mt * 16 + q * 4;
#pragma unroll
    for (int nt = 0; nt < 4; ++nt) {
      const int col = n0 + wc * 64 + nt * 16 + ln;
      if (EPI == EPI_OUT && col >= 32) continue;
      const float bs = bias[col];
      const int ldc = (EPI == EPI_OUT) ? 32 : N;
#pragma unroll
      for (int r = 0; r < 4; ++r) {
        float v = acc[mt][nt][r] + bs;
        if (EPI == EPI_RELU) v = fmaxf(v, 0.f);
        C[(size_t)(rowb + r) * ldc + col] = f2bf(v);
      }
    }
  }
}

// ---------------------------------------------------------------------------
// V transpose: big V-cols [32768 tok x 1536 (+1024 off)] -> vt[(seq*8+h)*64+hd][512 key]
// grid (512 = seq*8+h, 8 key-tiles), block 256.
// ---------------------------------------------------------------------------
__global__ __launch_bounds__(256) void vt_k(const unsigned short* __restrict__ big,
                                            unsigned short* __restrict__ vt) {
  __shared__ unsigned short td[64 * 72];
  const int tid = threadIdx.x;
  const int sh = blockIdx.x;           // seq*8 + h
  const int seq = sh >> 3, h = sh & 7;
  const int kt = blockIdx.y;           // key tile of 64
  {
    const int key = tid >> 2, hdc = (tid & 3) << 4;
    const unsigned short* src =
        big + ((size_t)seq * 512 + kt * 64 + key) * 1536 + 1024 + h * 64 + hdc;
    *(u16x8*)(td + key * 72 + hdc) = *(const u16x8*)src;
    *(u16x8*)(td + key * 72 + hdc + 8) = *(const u16x8*)(src + 8);
  }
  __syncthreads();
  {
    const int hd = tid >> 2, kc = (tid & 3) << 4;
    u16x8 a, b;
#pragma unroll
    for (int j = 0; j < 8; ++j) a[j] = td[(kc + j) * 72 + hd];
#pragma unroll
    for (int j = 0; j < 8; ++j) b[j] = td[(kc + 8 + j) * 72 + hd];
    unsigned short* dst = vt + ((size_t)sh * 64 + hd) * 512 + kt * 64 + kc;
    *(u16x8*)dst = a;
    *(u16x8*)(dst + 8) = b;
  }
}

// ---------------------------------------------------------------------------
// Flash attention with alibi, NO max-subtraction (scores bounded; exp2 direct).
// qkv: [32768 tok x 1536] bf16 (q|k|v), vt: pre-transposed V [sh*64+hd][512].
// grid (seq*8, qt=4), block 256. Writes o [32768 x 512] bf16.
// ---------------------------------------------------------------------------
__global__ __launch_bounds__(256) void attn_k(const unsigned short* __restrict__ qkv,
                                              const unsigned short* __restrict__ vt,
                                              unsigned short* __restrict__ o) {
  __shared__ unsigned short Qs[128 * 72];
  __shared__ unsigned short Ks[64 * 72];
  __shared__ unsigned short Vts[64 * 72];  // [hd][key] (from vt, stride-72)
  __shared__ unsigned short Ps[128 * 72];
  const int tid = threadIdx.x;
  const int lane = tid & 63, w = tid >> 6, q = lane >> 4, ln = lane & 15;
  const int bh = blockIdx.x;
  const int seq = bh >> 3, h = bh & 7;
  const int qt = blockIdx.y;
  const size_t tokb = (size_t)seq * 512;
  const int qoff = h * 64, koff = 512 + h * 64;
  const float c1 = 0.125f * 1.44269504f;               // scale * log2e
  const float c2 = ((h < 4) ? 1.0f : 0.5f) * 1.44269504f;  // slope * log2e

#pragma unroll
  for (int p = 0; p < 4; ++p) {  // stage Q 128x64
    int c = p * 256 + tid;
    int row = c >> 3, cc = (c & 7) << 3;
    u16x8 v = *(const u16x8*)(qkv + (tokb + qt * 128 + row) * 1536 + qoff + cc);
    *(u16x8*)(Qs + row * 72 + cc) = v;
  }
  __syncthreads();
  u16x8 aq[2][2];
#pragma unroll
  for (int mt = 0; mt < 2; ++mt)
#pragma unroll
    for (int kc = 0; kc < 2; ++kc)
      aq[mt][kc] = *(const u16x8*)(Qs + (w * 32 + mt * 16 + ln) * 72 + kc * 32 + q * 8);

  float lacc[2][4];
  f32x4 o_acc[2][4];
#pragma unroll
  for (int mt = 0; mt < 2; ++mt)
#pragma unroll
    for (int r = 0; r < 4; ++r) lacc[mt][r] = 0.f;
#pragma unroll
  for (int mt = 0; mt < 2; ++mt)
#pragma unroll
    for (int ht = 0; ht < 4; ++ht) o_acc[mt][ht] = zero4();

  const int krow = tid >> 3, kcc = (tid & 7) << 3;
  const int vhd = tid >> 2, vc = (tid & 3) << 4;
  const unsigned short* vbase = vt + ((size_t)bh * 64 + vhd) * 512 + vc;

  for (int kt = 0; kt < 8; ++kt) {
    __syncthreads();
    {
      u16x8 v0 = *(const u16x8*)(qkv + (tokb + kt * 64 + krow) * 1536 + koff + kcc);
      u16x8 v1 = *(const u16x8*)(qkv + (tokb + kt * 64 + krow + 32) * 1536 + koff + kcc);
      *(u16x8*)(Ks + krow * 72 + kcc) = v0;
      *(u16x8*)(Ks + (krow + 32) * 72 + kcc) = v1;
      u16x8 w0 = *(const u16x8*)(vbase + kt * 64);
      u16x8 w1 = *(const u16x8*)(vbase + kt * 64 + 8);
      *(u16x8*)(Vts + vhd * 72 + vc) = w0;
      *(u16x8*)(Vts + vhd * 72 + vc + 8) = w1;
    }
    __syncthreads();

    f32x4 sacc[2][4];
#pragma unroll
    for (int mt = 0; mt < 2; ++mt)
#pragma unroll
      for (int nt = 0; nt < 4; ++nt) sacc[mt][nt] = zero4();
#pragma unroll
    for (int nt = 0; nt < 4; ++nt)
#pragma unroll
      for (int kc = 0; kc < 2; ++kc) {
        u16x8 bk = *(const u16x8*)(Ks + (nt * 16 + ln) * 72 + kc * 32 + q * 8);
#pragma unroll
        for (int mt = 0; mt < 2; ++mt) sacc[mt][nt] = mfma16(aq[mt][kc], bk, sacc[mt][nt]);
      }

    // P = exp2(S*c1 - c2*|dq-dk|); no max-subtract, no rescale.
    const float kbase = (float)(kt * 64 + ln);
#pragma unroll
    for (int mt = 0; mt < 2; ++mt) {
      const float qpb = (float)(qt * 128 + w * 32 + mt * 16 + q * 4);
#pragma unroll
      for (int nt = 0; nt < 4; ++nt) {
        const float kp = kbase + (float)(nt * 16);
#pragma unroll
        for (int r = 0; r < 4; ++r) {
          const float ad = fabsf(qpb + (float)r - kp);
          const float p = exp2f(fmaf(sacc[mt][nt][r], c1, -c2 * ad));
          const unsigned u = __builtin_bit_cast(unsigned, p);
          const unsigned short pb = (unsigned short)((u + 0x8000u) >> 16);
          Ps[(w * 32 + mt * 16 + q * 4 + r) * 72 + nt * 16 + ln] = pb;
          lacc[mt][r] += bf2f(pb);  // sum of the *stored* values -> div cancels bias
        }
      }
    }
    // P @ V  (Ps rows are wave-private; in-wave LDS ordering suffices)
#pragma unroll
    for (int kc = 0; kc < 2; ++kc) {
      u16x8 pa[2];
#pragma unroll
      for (int mt = 0; mt < 2; ++mt)
        pa[mt] = *(const u16x8*)(Ps + (w * 32 + mt * 16 + ln) * 72 + kc * 32 + q * 8);
#pragma unroll
      for (int ht = 0; ht < 4; ++ht) {
        u16x8 bv = *(const u16x8*)(Vts + (ht * 16 + ln) * 72 + kc * 32 + q * 8);
#pragma unroll
        for (int mt = 0; mt < 2; ++mt) o_acc[mt][ht] = mfma16(pa[mt], bv, o_acc[mt][ht]);
      }
    }
  }

  float rl[2][4];
#pragma unroll
  for (int mt = 0; mt < 2; ++mt)
#pragma unroll
    for (int r = 0; r < 4; ++r) {
      float l = lacc[mt][r];
#pragma unroll
      for (int msk = 1; msk < 16; msk <<= 1) l += __shfl_xor(l, msk, 64);
      rl[mt][r] = 1.0f / l;
    }

#pragma unroll
  for (int mt = 0; mt < 2; ++mt)
#pragma unroll
    for (int ht = 0; ht < 4; ++ht)
#pragma unroll
      for (int r = 0; r < 4; ++r) {
        const int row = qt * 128 + w * 32 + mt * 16 + q * 4 + r;
        const float val = o_acc[mt][ht][r] * rl[mt][r];
        o[(tokb + row) * 512 + h * 64 + ht * 16 + ln] = f2bf(val);
      }
}

// ---------------------------------------------------------------------------
// Fused residual + LayerNorm (in-place capable)
// ---------------------------------------------------------------------------
__global__ __launch_bounds__(256) void ln_k(const unsigned short* res,
                                            const unsigned short* __restrict__ y,
                                            const float* __restrict__ g,
                                            const float* __restrict__ b,
                                            unsigned short* out) {
  const int lane = threadIdx.x & 63, wv = threadIdx.x >> 6;
  const size_t row = (size_t)blockIdx.x * 4 + wv;
  const size_t base = row * 512 + lane * 8;
  u16x8 rv = *(const u16x8*)(res + base);
  u16x8 yv = *(const u16x8*)(y + base);
  float v[8];
  float s = 0.f, s2 = 0.f;
#pragma unroll
  for (int i = 0; i < 8; ++i) {
    v[i] = bf2f(rv[i]) + bf2f(yv[i]);
    s += v[i];
    s2 += v[i] * v[i];
  }
#pragma unroll
  for (int m = 1; m < 64; m <<= 1) {
    s += __shfl_xor(s, m, 64);
    s2 += __shfl_xor(s2, m, 64);
  }
  const float mean = s * (1.f / 512.f);
  const float var = s2 * (1.f / 512.f) - mean * mean;
  const float rstd = rsqrtf(var + 1e-5f);
  const int c = lane * 8;
  u16x8 ov;
#pragma unroll
  for (int i = 0; i < 8; ++i) ov[i] = f2bf((v[i] - mean) * rstd * g[c + i] + b[c + i]);
  *(u16x8*)(out + base) = ov;
}

// ---------------------------------------------------------------------------
// Weight transpose fp32 (Kin x Nin) -> bf16 (Nout x Kout), zero-padded.
// ---------------------------------------------------------------------------
__global__ __launch_bounds__(256) void transpose_w(const float* __restrict__ in,
                                                   unsigned short* __restrict__ out,
                                                   int Kin, int Nin, int Kout, int Nout) {
  __shared__ float tile[32][33];
  const int nb = blockIdx.x * 32, kb = blockIdx.y * 32;
  const int tx = threadIdx.x & 31, ty = threadIdx.x >> 5;
#pragma unroll
  for (int i = 0; i < 32; i += 8) {
    int k = kb + ty + i, n = nb + tx;
    tile[ty + i][tx] = (k < Kin && n < Nin) ? in[(size_t)k * Nin + n] : 0.f;
  }
  __syncthreads();
#pragma unroll
  for (int i = 0; i < 32; i += 8) {
    int n = nb + ty + i, k = kb + tx;
    if (n < Nout && k < Kout) out[(size_t)n * Kout + k] = f2bf(tile[tx][ty + i]);
  }
}

// x (64 x 20480) fp32 -> xpad (65536 tok x 64) bf16 (K padded 20->64 for BK=64)
__global__ __launch_bounds__(256) void xpad_k(const float* __restrict__ x,
                                              unsigned short* __restrict__ xp) {
  const int idx = blockIdx.x * 256 + threadIdx.x;  // 65536*64
  const int tok = idx >> 6, k = idx & 63;
  const int seq = tok >> 9, s = tok & 511;
  const int hf = seq >> 6, b = seq & 63;
  float v = 0.f;
  if (k < 20) v = x[(size_t)b * 20480 + hf * 10240 + s * 20 + k];
  xp[idx] = f2bf(v);
}

// ---------------------------------------------------------------------------
// Head d1: h(64 x 32768) @ d1_W(32768 x 256). 256 K-slices of 128; W read once.
// ---------------------------------------------------------------------------
__global__ __launch_bounds__(256) void d1_part(const unsigned short* __restrict__ enc,
                                               const float* __restrict__ W,
                                               float* __restrict__ pz) {
  __shared__ float ef[64 * 128];  // 32 KB
  const int tid = threadIdx.x;
  const int kb = blockIdx.x * 128;
  const int hf = kb >> 14;
  const int j0 = kb & 16383;
  {
    const int m = tid >> 2, c = (tid & 3) * 32;
    const unsigned short* src = enc + (size_t)hf * 1048576 + (size_t)m * 16384 + j0 + c;
#pragma unroll
    for (int i = 0; i < 4; ++i) {
      u16x8 v = *(const u16x8*)(src + i * 8);
#pragma unroll
      for (int jj = 0; jj < 8; ++jj) ef[m * 128 + c + i * 8 + jj] = bf2f(v[jj]);
    }
  }
  __syncthreads();
  const int n = tid;
  float acc[64];
#pragma unroll
  for (int m = 0; m < 64; ++m) acc[m] = 0.f;
  for (int kc = 0; kc < 128; kc += 4) {
    const float w0 = W[(size_t)(kb + kc) * 256 + n];
    const float w1 = W[(size_t)(kb + kc + 1) * 256 + n];
    const float w2 = W[(size_t)(kb + kc + 2) * 256 + n];
    const float w3 = W[(size_t)(kb + kc + 3) * 256 + n];
#pragma unroll
    for (int m = 0; m < 64; ++m) {
      const f32x4 e = *(const f32x4*)(ef + m * 128 + kc);
      acc[m] += e[0] * w0 + e[1] * w1 + e[2] * w2 + e[3] * w3;
    }
  }
#pragma unroll
  for (int m = 0; m < 64; ++m)
    pz[(size_t)(blockIdx.x * 64 + m) * 256 + n] = acc[m];
}

__global__ __launch_bounds__(256) void d1_fin(const float* __restrict__ pz,
                                              const float* __restrict__ d1b,
                                              const float* __restrict__ g,
                                              const float* __restrict__ b,
                                              const float* __restrict__ mm,
                                              const float* __restrict__ vv,
                                              float* __restrict__ h1) {
  const int m = blockIdx.x, n = threadIdx.x;
  float a = d1b[n];
  for (int sl = 0; sl < 256; ++sl) a += pz[(size_t)(sl * 64 + m) * 256 + n];
  a = fmaxf(a, 0.f);
  a = (a - mm[n]) * rsqrtf(vv[n] + 1e-5f) * g[n] + b[n];
  h1[m * 256 + n] = a;
}

__global__ __launch_bounds__(128) void d2_k(const float* __restrict__ h1,
                                            const float* __restrict__ W,
                                            const float* __restrict__ bb,
                                            const float* __restrict__ g,
                                            const float* __restrict__ b,
                                            const float* __restrict__ mm,
                                            const float* __restrict__ vv,
                                            float* __restrict__ h2) {
  __shared__ float hs[256];
  const int m = blockIdx.x, n = threadIdx.x;
  hs[n] = h1[m * 256 + n];
  hs[n + 128] = h1[m * 256 + n + 128];
  __syncthreads();
  float a = bb[n];
#pragma unroll 8
  for (int k = 0; k < 256; ++k) a += hs[k] * W[k * 128 + n];
  a = fmaxf(a, 0.f);
  a = (a - mm[n]) * rsqrtf(vv[n] + 1e-5f) * g[n] + b[n];
  h2[m * 128 + n] = a;
}

__global__ __launch_bounds__(64) void fin_k(const float* __restrict__ h2,
                                            const float* __restrict__ W,
                                            const float* __restrict__ fb,
                                            float* __restrict__ out) {
  const int m = threadIdx.x;
  float a = fb[0];
#pragma unroll 8
  for (int k = 0; k < 128; ++k) a += h2[m * 128 + k] * W[k];
  out[m] = a;
}

// ---------------------------------------------------------------------------
extern "C" void kernel_launch(void* const* d_in, const int* in_sizes, int n_in,
                              void* d_out, int out_size, void* d_ws, size_t ws_size,
                              hipStream_t stream) {
  const float* x      = (const float*)d_in[0];
  const float* in_W   = (const float*)d_in[1];
  const float* in_b   = (const float*)d_in[2];
  const float* qkv_W  = (const float*)d_in[3];
  const float* qkv_b  = (const float*)d_in[4];
  const float* ln1_g  = (const float*)d_in[5];
  const float* ln1_b  = (const float*)d_in[6];
  const float* ffn_W1 = (const float*)d_in[7];
  const float* ffn_b1 = (const float*)d_in[8];
  const float* ffn_W2 = (const float*)d_in[9];
  const float* ffn_b2 = (const float*)d_in[10];
  const float* ln2_g  = (const float*)d_in[11];
  const float* ln2_b  = (const float*)d_in[12];
  const float* out_W  = (const float*)d_in[13];
  const float* out_b  = (const float*)d_in[14];
  const float* d1W    = (const float*)d_in[15];
  const float* d1b    = (const float*)d_in[16];
  const float* bn1g   = (const float*)d_in[17];
  const float* bn1b   = (const float*)d_in[18];
  const float* bn1m   = (const float*)d_in[19];
  const float* bn1v   = (const float*)d_in[20];
  const float* d2W    = (const float*)d_in[21];
  const float* d2b    = (const float*)d_in[22];
  const float* bn2g   = (const float*)d_in[23];
  const float* bn2b   = (const float*)d_in[24];
  const float* bn2m   = (const float*)d_in[25];
  const float* bn2v   = (const float*)d_in[26];
  const float* finW   = (const float*)d_in[27];
  const float* finb   = (const float*)d_in[28];
  (void)in_sizes; (void)n_in; (void)out_size; (void)ws_size;

  char* ws = (char*)d_ws;
  size_t off = 0;
  auto alloc = [&](size_t bytes) {
    char* p = ws + off;
    off += (bytes + 255) & ~(size_t)255;
    return p;
  };
  unsigned short* t     = (unsigned short*)alloc(32768ull * 512 * 2);   //  33.5 MB
  unsigned short* big   = (unsigned short*)alloc(32768ull * 2048 * 2);  // 134 MB (qkv+vt / f1 / pz)
  unsigned short* ob    = (unsigned short*)alloc(32768ull * 512 * 2);   //  33.5 MB (o / y)
  unsigned short* xpad  = (unsigned short*)alloc(65536ull * 64 * 2);    //   8.4 MB (K padded to 64)
  unsigned short* enc   = (unsigned short*)alloc(65536ull * 32 * 2);
  unsigned short* inWt  = (unsigned short*)alloc(512ull * 64 * 2);
  unsigned short* qkvWt = (unsigned short*)alloc(4ull * 1536 * 512 * 2);
  unsigned short* f1Wt  = (unsigned short*)alloc(4ull * 2048 * 512 * 2);
  unsigned short* f2Wt  = (unsigned short*)alloc(4ull * 512 * 2048 * 2);
  unsigned short* outWt = (unsigned short*)alloc(128ull * 512 * 2);
  float* h1 = (float*)alloc(64ull * 256 * 4);
  float* h2 = (float*)alloc(64ull * 128 * 4);
  float* pz = (float*)big;                               // big free by d1 time
  unsigned short* vtb = big + (size_t)32768 * 1536;      // upper 33.5 MB of big

  xpad_k<<<16384, 256, 0, stream>>>(x, xpad);
  transpose_w<<<dim3(16, 2), 256, 0, stream>>>(in_W, inWt, 20, 512, 64, 512);
  transpose_w<<<dim3(4, 16), 256, 0, stream>>>(out_W, outWt, 512, 32, 512, 128);
  for (int l = 0; l < 4; ++l) {
    transpose_w<<<dim3(48, 16), 256, 0, stream>>>(qkv_W + (size_t)l * 512 * 1536,
                                                  qkvWt + (size_t)l * 1536 * 512, 512, 1536, 512, 1536);
    transpose_w<<<dim3(64, 16), 256, 0, stream>>>(ffn_W1 + (size_t)l * 512 * 2048,
                                                  f1Wt + (size_t)l * 2048 * 512, 512, 2048, 512, 2048);
    transpose_w<<<dim3(16, 64), 256, 0, stream>>>(ffn_W2 + (size_t)l * 2048 * 512,
                                                  f2Wt + (size_t)l * 512 * 2048, 2048, 512, 2048, 512);
  }

  for (int hf = 0; hf < 2; ++hf) {
    gemm_k<EPI_BIAS><<<dim3(4, 256), 256, 0, stream>>>(xpad + (size_t)hf * 32768 * 64, inWt, in_b, t, 512, 64);
    for (int l = 0; l < 4; ++l) {
      gemm_k<EPI_BIAS><<<dim3(12, 256), 256, 0, stream>>>(t, qkvWt + (size_t)l * 1536 * 512,
                                                          qkv_b + l * 1536, big, 1536, 512);
      vt_k<<<dim3(512, 8), 256, 0, stream>>>(big, vtb);
      attn_k<<<dim3(512, 4), 256, 0, stream>>>(big, vtb, ob);
      ln_k<<<8192, 256, 0, stream>>>(t, ob, ln1_g + l * 512, ln1_b + l * 512, t);
      gemm_k<EPI_RELU><<<dim3(16, 256), 256, 0, stream>>>(t, f1Wt + (size_t)l * 2048 * 512,
                                                          ffn_b1 + l * 2048, big, 2048, 512);
      gemm_k<EPI_BIAS><<<dim3(4, 256), 256, 0, stream>>>(big, f2Wt + (size_t)l * 512 * 2048,
                                                         ffn_b2 + l * 512, ob, 512, 2048);
      ln_k<<<8192, 256, 0, stream>>>(t, ob, ln2_g + l * 512, ln2_b + l * 512, t);
    }
    gemm_k<EPI_OUT><<<dim3(1, 256), 256, 0, stream>>>(t, outWt, out_b,
                                                      enc + (size_t)hf * 32768 * 32, 128, 512);
  }

  d1_part<<<256, 256, 0, stream>>>(enc, d1W, pz);
  d1_fin<<<64, 256, 0, stream>>>(pz, d1b, bn1g, bn1b, bn1m, bn1v, h1);
  d2_k<<<64, 128, 0, stream>>>(h1, d2W, d2b, bn2g, bn2b, bn2m, bn2v, h2);
  fin_k<<<1, 64, 0, stream>>>(h2, finW, finb, (float*)d_out);
}